// Round 4
// baseline (363.166 us; speedup 1.0000x reference)
//
#include <hip/hip_runtime.h>
#include <hip/hip_bf16.h>
#include <math.h>

#define B_   4
#define S_   512
#define D_   1024
#define H_   16
#define E_   4
#define HD_  64
#define D2_  512
#define NTOK (B_*S_)   // 2048

#define TDE ((size_t)NTOK * D_)   // elements of one [NTOK,D] buffer
#define WWE ((size_t)D_ * D_)     // elements of one [D,D] weight
#define ND2 ((size_t)NTOK * D2_)

typedef unsigned short ushort;
typedef short shortv8 __attribute__((ext_vector_type(8)));
typedef ushort ushortv8 __attribute__((ext_vector_type(8)));
typedef ushort ushortv4 __attribute__((ext_vector_type(4)));
typedef float floatv4 __attribute__((ext_vector_type(4)));

__device__ __forceinline__ ushort f2bf(float f) {
    union { __hip_bfloat16 b; ushort u; } cv;
    cv.b = __float2bfloat16(f);
    return cv.u;
}
__device__ __forceinline__ float bf2f(ushort u) {
    union { ushort u; __hip_bfloat16 b; } cv;
    cv.u = u;
    return __bfloat162float(cv.b);
}
__device__ __forceinline__ void splitbf(float v, ushort& hi, ushort& lo) {
    hi = f2bf(v);
    lo = f2bf(v - bf2f(hi));
}
__device__ __forceinline__ void gload16(const ushort* g, ushort* l) {
    __builtin_amdgcn_global_load_lds(
        (const __attribute__((address_space(1))) unsigned int*)g,
        (__attribute__((address_space(3))) unsigned int*)l, 16, 0, 0);
}

// ---------------------------------------------------------------------------
// Split-bf16 GEMM core (validated r2/r3). GATHER=true: A rows from arow[]
// (int list, bit31 = pad flag, low bits = source row). 128x128, BK=32,
// 4 waves, 3-term split (ah*bh + ah*bl + al*bh).
// ---------------------------------------------------------------------------
template<bool GATHER>
__device__ __forceinline__ void gemm_core_t(
    const ushort* __restrict__ A0, const ushort* __restrict__ A1,
    const ushort* __restrict__ B0, const ushort* __restrict__ B1,
    const int* __restrict__ arow,   // idx list offset to brow (GATHER only)
    int K, int klen, int brow, int bcol, ushort* lds, floatv4 acc[4][4])
{
    const int tid  = threadIdx.x;
    const int wave = tid >> 6, lane = tid & 63;
    const int wm = wave >> 1, wn = wave & 1;
    const int lr = lane & 15, lc = lane >> 4;

    const ushort* gsrc[4] = {A0, A1, B0, B1};
    size_t  goff[4][2];
    ushort* ldst[4][2];
#pragma unroll
    for (int t = 0; t < 4; t++) {
#pragma unroll
        for (int s = 0; s < 2; s++) {
            int p = s * 256 + tid;
            int m = p >> 2;
            int c = (p & 3) ^ ((m >> 1) & 3);
            int r;
            if (t < 2) r = GATHER ? (arow[m] & 0x7FFFFFFF) : (brow + m);
            else       r = bcol + m;
            goff[t][s] = (size_t)r * K + c * 8;
            ldst[t][s] = lds + t * 4096 + p * 8;
        }
    }

    int aoff[4], boff[4];
#pragma unroll
    for (int i = 0; i < 4; i++) {
        int ra = wm * 64 + i * 16 + lr;
        aoff[i] = ra * 32 + ((lc ^ ((ra >> 1) & 3)) * 8);
        int rb2 = wn * 64 + i * 16 + lr;
        boff[i] = rb2 * 32 + ((lc ^ ((rb2 >> 1) & 3)) * 8);
    }

    for (int k0 = 0; k0 < klen; k0 += 32) {
        __syncthreads();
#pragma unroll
        for (int t = 0; t < 4; t++)
#pragma unroll
            for (int s = 0; s < 2; s++)
                gload16(gsrc[t] + goff[t][s] + k0, ldst[t][s]);
        __syncthreads();

        shortv8 ah[4], al[4], bh[4], bl[4];
#pragma unroll
        for (int i = 0; i < 4; i++) {
            ah[i] = *(const shortv8*)(lds +         aoff[i]);
            al[i] = *(const shortv8*)(lds +  4096 + aoff[i]);
            bh[i] = *(const shortv8*)(lds +  8192 + boff[i]);
            bl[i] = *(const shortv8*)(lds + 12288 + boff[i]);
        }
#pragma unroll
        for (int mi = 0; mi < 4; mi++)
#pragma unroll
            for (int nj = 0; nj < 4; nj++) {
                acc[mi][nj] = __builtin_amdgcn_mfma_f32_16x16x32_bf16(ah[mi], bh[nj], acc[mi][nj], 0, 0, 0);
                acc[mi][nj] = __builtin_amdgcn_mfma_f32_16x16x32_bf16(ah[mi], bl[nj], acc[mi][nj], 0, 0, 0);
                acc[mi][nj] = __builtin_amdgcn_mfma_f32_16x16x32_bf16(al[mi], bh[nj], acc[mi][nj], 0, 0, 0);
            }
    }
}

#define ACC_INIT(acc) \
    _Pragma("unroll") for (int i = 0; i < 4; i++) \
    _Pragma("unroll") for (int j = 0; j < 4; j++) \
    _Pragma("unroll") for (int q = 0; q < 4; q++) acc[i][j][q] = 0.f;

#define EPI_VARS \
    const int lane = threadIdx.x & 63, wave = threadIdx.x >> 6; \
    const int wm = wave >> 1, wn = wave & 1, lr = lane & 15, lc = lane >> 4;

// ---- Router hidden GEMM, split-K x4 ----
__global__ __launch_bounds__(256, 2) void gemm_router(
    const ushort* __restrict__ xh, const ushort* __restrict__ xl,
    const ushort* __restrict__ wr1h, const ushort* __restrict__ wr1l,
    float* __restrict__ hpart)
{
    __shared__ ushort lds[16384];
    floatv4 acc[4][4];
    ACC_INIT(acc)

    const int kz = blockIdx.z;
    const int koff = kz * 256;
    const int brow = blockIdx.y * 128, bcol = blockIdx.x * 128;
    gemm_core_t<false>(xh + koff, xl + koff, wr1h + koff, wr1l + koff,
                       nullptr, D_, 256, brow, bcol, lds, acc);

    float* C = hpart + (size_t)kz * ND2;
    EPI_VARS
#pragma unroll
    for (int mi = 0; mi < 4; mi++)
#pragma unroll
        for (int nj = 0; nj < 4; nj++)
#pragma unroll
            for (int i = 0; i < 4; i++) {
                int row = brow + wm * 64 + mi * 16 + lc * 4 + i;
                int col = bcol + wn * 64 + nj * 16 + lr;
                C[(size_t)row * D2_ + col] = acc[mi][nj][i];
            }
}

// ---- Dense K/V projections: z = slot*2 + m (m: 0=K hi/lo, 1=V plain) ----
__global__ __launch_bounds__(256, 2) void gemm_kv_all(
    const ushort* __restrict__ xh, const ushort* __restrict__ xl,
    const ushort* __restrict__ wth, const ushort* __restrict__ wtl,
    const float* __restrict__ bk, const float* __restrict__ bv,
    ushort* __restrict__ kh, ushort* __restrict__ kl, ushort* __restrict__ vb)
{
    __shared__ ushort lds[16384];
    const int slot = blockIdx.z >> 1, m = blockIdx.z & 1;
    const size_t so = (size_t)slot * TDE;
    const ushort* B0 = wth + (size_t)(slot * 4 + 1 + m) * WWE;   // mat 1=K, 2=V
    const ushort* B1 = wtl + (size_t)(slot * 4 + 1 + m) * WWE;
    const float* bias = ((m == 0) ? bk : bv) + (size_t)slot * D_;
    ushort* Oh = ((m == 0) ? kh : vb) + so;
    ushort* Ol = (m == 0) ? kl + so : nullptr;

    floatv4 acc[4][4];
    ACC_INIT(acc)

    const int brow = blockIdx.y * 128, bcol = blockIdx.x * 128;
    gemm_core_t<false>(xh, xl, B0, B1, nullptr, D_, D_, brow, bcol, lds, acc);

    EPI_VARS
#pragma unroll
    for (int mi = 0; mi < 4; mi++)
#pragma unroll
        for (int nj = 0; nj < 4; nj++)
#pragma unroll
            for (int i = 0; i < 4; i++) {
                int row = brow + wm * 64 + mi * 16 + lc * 4 + i;
                int col = bcol + wn * 64 + nj * 16 + lr;
                float val = acc[mi][nj][i] + bias[col];
                ushort h = f2bf(val);
                Oh[(size_t)row * D_ + col] = h;
                if (Ol) Ol[(size_t)row * D_ + col] = f2bf(val - bf2f(h));
            }
}

// ---- Gathered Q projection: z = expert, rows = compacted routed tokens ----
__global__ __launch_bounds__(256, 2) void gemm_q_gather(
    const ushort* __restrict__ xh, const ushort* __restrict__ xl,
    const ushort* __restrict__ wth, const ushort* __restrict__ wtl,
    const float* __restrict__ bq, const int* __restrict__ idx,
    const int* __restrict__ meta, ushort* __restrict__ qh, ushort* __restrict__ ql)
{
    __shared__ ushort lds[16384];
    const int e = blockIdx.z;
    const int pcnt = meta[32 + e];
    const int brow = blockIdx.y * 128;
    if (brow >= pcnt) return;
    const int bcol = blockIdx.x * 128;
    const int* arow = idx + e * 2048 + brow;
    const ushort* B0 = wth + (size_t)(e * 4 + 0) * WWE;
    const ushort* B1 = wtl + (size_t)(e * 4 + 0) * WWE;
    const float* bias = bq + (size_t)e * D_;
    const size_t so = (size_t)e * TDE;

    floatv4 acc[4][4];
    ACC_INIT(acc)
    gemm_core_t<true>(xh, xl, B0, B1, arow, D_, D_, brow, bcol, lds, acc);

    EPI_VARS
#pragma unroll
    for (int mi = 0; mi < 4; mi++)
#pragma unroll
        for (int nj = 0; nj < 4; nj++)
#pragma unroll
            for (int i = 0; i < 4; i++) {
                int row = brow + wm * 64 + mi * 16 + lc * 4 + i;   // slot
                int col = bcol + wn * 64 + nj * 16 + lr;
                float val = (acc[mi][nj][i] + bias[col]) * 0.125f;
                ushort h = f2bf(val);
                qh[so + (size_t)row * D_ + col] = h;
                ql[so + (size_t)row * D_ + col] = f2bf(val - bf2f(h));
            }
}

// ---- Output projection on compacted rows + scatter into out4 slice ----
__global__ __launch_bounds__(256, 2) void gemm_combine4(
    const ushort* __restrict__ oh, const ushort* __restrict__ ol,
    const ushort* __restrict__ wth, const ushort* __restrict__ wtl,
    const float* __restrict__ bo, const float* __restrict__ emask,
    const int* __restrict__ idx, const int* __restrict__ meta,
    float* __restrict__ out4)
{
    __shared__ ushort lds[16384];
    const int e = blockIdx.z;
    const int pcnt = meta[32 + e];
    const int brow = blockIdx.y * 128;
    if (brow >= pcnt) return;
    const int bcol = blockIdx.x * 128;
    const size_t so = (size_t)e * TDE;
    const ushort* B0 = wth + (size_t)(e * 4 + 3) * WWE;
    const ushort* B1 = wtl + (size_t)(e * 4 + 3) * WWE;
    const float* bias = bo + (size_t)e * D_;
    const int* idxe = idx + e * 2048;

    floatv4 acc[4][4];
    ACC_INIT(acc)
    gemm_core_t<false>(oh + so, ol + so, B0, B1, nullptr, D_, D_, brow, bcol, lds, acc);

    float* dst = out4 + so;
    EPI_VARS
#pragma unroll
    for (int mi = 0; mi < 4; mi++)
#pragma unroll
        for (int nj = 0; nj < 4; nj++)
#pragma unroll
            for (int i = 0; i < 4; i++) {
                int srow = brow + wm * 64 + mi * 16 + lc * 4 + i;
                int raw = idxe[srow];
                if (raw >= 0) {   // bit31 = pad flag
                    float s = emask[(size_t)raw * E_ + e];
                    int col = bcol + wn * 64 + nj * 16 + lr;
                    dst[(size_t)raw * D_ + col] = s * (acc[mi][nj][i] + bias[col]);
                }
            }
}

// ---- reduce out4 slices -> out ----
__global__ __launch_bounds__(256) void reduce_out(
    const float* __restrict__ out4, float* __restrict__ out)
{
    size_t i = (size_t)blockIdx.x * 256 + threadIdx.x;
    const float4* p = (const float4*)out4;
    float4 a = p[i], b = p[i + TDE / 4], c = p[i + 2 * (TDE / 4)], d = p[i + 3 * (TDE / 4)];
    float4 r;
    r.x = a.x + b.x + c.x + d.x;
    r.y = a.y + b.y + c.y + d.y;
    r.z = a.z + b.z + c.z + d.z;
    r.w = a.w + b.w + c.w + d.w;
    ((float4*)out)[i] = r;
}

// ---------------------------------------------------------------------------
// Per-(expert,batch) routed-token lists, 64-padded, deterministic order.
// idx[e][slot] = token | (bit31 if pad). meta: pstart[4][4] @0, ptiles[4][4]
// @16, pcnt[4] @32.
// ---------------------------------------------------------------------------
__global__ __launch_bounds__(256) void build_lists(
    const float* __restrict__ emask, int* __restrict__ idx, int* __restrict__ meta)
{
    const int e = blockIdx.x;
    const int tid = threadIdx.x;
    __shared__ int scan[256];
    __shared__ int runsh;
    if (tid == 0) runsh = 0;
    int* idxe = idx + e * 2048;

    for (int b = 0; b < B_; b++) {
        __syncthreads();
        const int base = runsh;
        int t0 = b * 512 + tid * 2;
        int f0 = (emask[(size_t)t0 * E_ + e] != 0.f) ? 1 : 0;
        int f1 = (emask[(size_t)(t0 + 1) * E_ + e] != 0.f) ? 1 : 0;
        int my = f0 + f1;
        scan[tid] = my;
        __syncthreads();
        for (int off = 1; off < 256; off <<= 1) {
            int v = (tid >= off) ? scan[tid - off] : 0;
            __syncthreads();
            scan[tid] += v;
            __syncthreads();
        }
        int excl = scan[tid] - my;
        int cnt = scan[255];
        if (f0) idxe[base + excl] = t0;
        if (f1) idxe[base + excl + f0] = t0 + 1;
        int plen = (cnt + 63) & ~63;
        for (int i = cnt + tid; i < plen; i += 256)
            idxe[base + i] = (b * 512) | (int)0x80000000;
        if (tid == 0) {
            meta[e * 4 + b] = base;
            meta[16 + e * 4 + b] = plen >> 6;
            runsh = base + plen;
        }
    }
    __syncthreads();
    int total = runsh;
    if (tid == 0) meta[32 + e] = total;
    for (int i = total + tid; i < 2048; i += 256)
        idxe[i] = (int)0x80000000;
}

// ---------------------------------------------------------------------------
// MFMA flash attention on compacted Q rows. grid (8, B*H, E); per-(e,b)
// Q-tile count from meta. K/V dense (all tokens are keys).
// ---------------------------------------------------------------------------
__global__ __launch_bounds__(256, 2) void attn_all(
    const ushort* __restrict__ qh_, const ushort* __restrict__ ql_,
    const ushort* __restrict__ kh_, const ushort* __restrict__ kl_,
    const ushort* __restrict__ vv_,
    ushort* __restrict__ oh_, ushort* __restrict__ ol_,
    const int* __restrict__ meta)
{
    const int e = blockIdx.z;
    const int bhid = blockIdx.y, bb = bhid >> 4, hh = bhid & 15;
    const int ptiles = meta[16 + e * 4 + bb];
    if ((int)blockIdx.x >= ptiles) return;
    const int pstart = meta[e * 4 + bb];

    __shared__ ushort Kh[4096], Kl[4096];   // [64][64] bf16, swizzled
    __shared__ ushort Vt[64 * 72];          // [d][k+pad]
    __shared__ ushort Pw[4][16 * 72];       // per-wave P

    const size_t zo = (size_t)e * TDE;
    const int tid = threadIdx.x;
    const int wave = tid >> 6, lane = tid & 63;
    const int lr = lane & 15, lc = lane >> 4;
    const int q0 = pstart + blockIdx.x * 64;                 // slot base
    const size_t kvbase = zo + (size_t)bb * S_ * D_ + hh * 64;
    const size_t qobase = zo + hh * 64;

    shortv8 qfh[2], qfl[2];
    {
        size_t qoff = qobase + (size_t)(q0 + wave * 16 + lr) * D_ + lc * 8;
        qfh[0] = *(const shortv8*)(qh_ + qoff);
        qfh[1] = *(const shortv8*)(qh_ + qoff + 32);
        qfl[0] = *(const shortv8*)(ql_ + qoff);
        qfl[1] = *(const shortv8*)(ql_ + qoff + 32);
    }

    floatv4 ov[4];
    float m4[4], l4[4];
#pragma unroll
    for (int df = 0; df < 4; df++)
#pragma unroll
        for (int i = 0; i < 4; i++) ov[df][i] = 0.f;
#pragma unroll
    for (int i = 0; i < 4; i++) { m4[i] = -3.0e38f; l4[i] = 0.f; }

    for (int kt = 0; kt < S_ / 64; kt++) {
        const int kk0 = kt * 64;
        __syncthreads();

#pragma unroll
        for (int t = 0; t < 2; t++) {
            const ushort* src = t ? kl_ : kh_;
            ushort* dst = t ? Kl : Kh;
#pragma unroll
            for (int s = 0; s < 2; s++) {
                int p = s * 256 + tid;
                int r = p >> 3;
                int c = (p & 7) ^ (r & 7);
                gload16(src + kvbase + (size_t)(kk0 + r) * D_ + c * 8, dst + p * 8);
            }
        }
        {
            const ushort* vsrc = vv_ + kvbase + (size_t)(kk0 + lane) * D_ + wave * 16;
            ushortv8 v0 = *(const ushortv8*)vsrc;
            ushortv8 v1 = *(const ushortv8*)(vsrc + 8);
#pragma unroll
            for (int j = 0; j < 8; j++) Vt[(wave * 16 + j) * 72 + lane] = v0[j];
#pragma unroll
            for (int j = 0; j < 8; j++) Vt[(wave * 16 + 8 + j) * 72 + lane] = v1[j];
        }
        __syncthreads();

        floatv4 sc[4];
#pragma unroll
        for (int n = 0; n < 4; n++)
#pragma unroll
            for (int i = 0; i < 4; i++) sc[n][i] = 0.f;
#pragma unroll
        for (int n = 0; n < 4; n++)
#pragma unroll
            for (int ds = 0; ds < 2; ds++) {
                int off = (16 * n + lr) * 64 + (((ds * 4 + lc) ^ (lr & 7)) * 8);
                shortv8 kfh = *(const shortv8*)(Kh + off);
                shortv8 kfl = *(const shortv8*)(Kl + off);
                sc[n] = __builtin_amdgcn_mfma_f32_16x16x32_bf16(qfh[ds], kfh, sc[n], 0, 0, 0);
                sc[n] = __builtin_amdgcn_mfma_f32_16x16x32_bf16(qfh[ds], kfl, sc[n], 0, 0, 0);
                sc[n] = __builtin_amdgcn_mfma_f32_16x16x32_bf16(qfl[ds], kfh, sc[n], 0, 0, 0);
            }

        float tm[4];
#pragma unroll
        for (int i = 0; i < 4; i++)
            tm[i] = fmaxf(fmaxf(sc[0][i], sc[1][i]), fmaxf(sc[2][i], sc[3][i]));
#pragma unroll
        for (int off = 1; off <= 8; off <<= 1)
#pragma unroll
            for (int i = 0; i < 4; i++)
                tm[i] = fmaxf(tm[i], __shfl_xor(tm[i], off));

        float nm[4], sca[4], ps[4];
#pragma unroll
        for (int i = 0; i < 4; i++) {
            nm[i] = fmaxf(m4[i], tm[i]);
            sca[i] = __expf(m4[i] - nm[i]);
            ps[i] = 0.f;
        }
        float pval[4][4];
#pragma unroll
        for (int n = 0; n < 4; n++)
#pragma unroll
            for (int i = 0; i < 4; i++) {
                float p = __expf(sc[n][i] - nm[i]);
                pval[n][i] = p;
                ps[i] += p;
            }
#pragma unroll
        for (int off = 1; off <= 8; off <<= 1)
#pragma unroll
            for (int i = 0; i < 4; i++)
                ps[i] += __shfl_xor(ps[i], off);
#pragma unroll
        for (int i = 0; i < 4; i++) {
            l4[i] = l4[i] * sca[i] + ps[i];
            m4[i] = nm[i];
        }
#pragma unroll
        for (int df = 0; df < 4; df++)
#pragma unroll
            for (int i = 0; i < 4; i++) ov[df][i] *= sca[i];

#pragma unroll
        for (int n = 0; n < 4; n++)
#pragma unroll
            for (int i = 0; i < 4; i++)
                Pw[wave][(lc * 4 + i) * 72 + 16 * n + lr] = f2bf(pval[n][i]);
        __syncthreads();

#pragma unroll
        for (int ks = 0; ks < 2; ks++) {
            shortv8 pa = *(const shortv8*)(&Pw[wave][lr * 72 + ks * 32 + lc * 8]);
#pragma unroll
            for (int df = 0; df < 4; df++) {
                shortv8 vf = *(const shortv8*)(Vt + (df * 16 + lr) * 72 + ks * 32 + lc * 8);
                ov[df] = __builtin_amdgcn_mfma_f32_16x16x32_bf16(pa, vf, ov[df], 0, 0, 0);
            }
        }
    }

#pragma unroll
    for (int df = 0; df < 4; df++)
#pragma unroll
        for (int i = 0; i < 4; i++) {
            float val = ov[df][i] / l4[i];
            size_t off = qobase + (size_t)(q0 + wave * 16 + lc * 4 + i) * D_ + df * 16 + lr;
            ushort h, l;
            splitbf(val, h, l);
            oh_[off] = h;
            ol_[off] = l;
        }
}

// ---------------------------------------------------------------------------
__global__ __launch_bounds__(256) void split_f32(
    const float* __restrict__ in, ushort* __restrict__ hi, ushort* __restrict__ lo)
{
    int i = blockIdx.x * 256 + threadIdx.x;
    float4 v = ((const float4*)in)[i];
    ushortv4 hv, lv;
    ushort h, l;
    splitbf(v.x, h, l); hv[0] = h; lv[0] = l;
    splitbf(v.y, h, l); hv[1] = h; lv[1] = l;
    splitbf(v.z, h, l); hv[2] = h; lv[2] = l;
    splitbf(v.w, h, l); hv[3] = h; lv[3] = l;
    ((ushortv4*)hi)[i] = hv;
    ((ushortv4*)lo)[i] = lv;
}

// ---------------------------------------------------------------------------
// Transpose + split: W[K][N] fp32 -> Th/Tl[N][K] bf16. 64x64 tiles.
// ---------------------------------------------------------------------------
__device__ __forceinline__ void tsplit_body(
    const float* __restrict__ W, ushort* __restrict__ Th, ushort* __restrict__ Tl,
    int K, int N, int n0, int k0)
{
    __shared__ float tile[64][65];
    const int tid = threadIdx.x;
#pragma unroll
    for (int i = 0; i < 16; i++) {
        int idx = i * 256 + tid;
        int r = idx >> 6, c = idx & 63;
        tile[r][c] = W[(size_t)(k0 + r) * N + n0 + c];
    }
    __syncthreads();
#pragma unroll
    for (int i = 0; i < 16; i++) {
        int idx = i * 256 + tid;
        int rn = idx >> 6, ck = idx & 63;
        float v = tile[ck][rn];
        ushort h, l;
        splitbf(v, h, l);
        Th[(size_t)(n0 + rn) * K + k0 + ck] = h;
        Tl[(size_t)(n0 + rn) * K + k0 + ck] = l;
    }
}

__global__ __launch_bounds__(256) void tsplit(
    const float* __restrict__ W, ushort* __restrict__ Th, ushort* __restrict__ Tl,
    int K, int N)
{
    tsplit_body(W, Th, Tl, K, N, blockIdx.x * 64, blockIdx.y * 64);
}

__global__ __launch_bounds__(256) void tsplit16(
    const float* __restrict__ Wq, const float* __restrict__ Wk,
    const float* __restrict__ Wv, const float* __restrict__ Wo,
    ushort* __restrict__ Th, ushort* __restrict__ Tl)
{
    const int mg = blockIdx.z;
    const int e = mg >> 2, m = mg & 3;
    const float* W = ((m == 0) ? Wq : (m == 1) ? Wk : (m == 2) ? Wv : Wo) + (size_t)e * WWE;
    tsplit_body(W, Th + (size_t)mg * WWE, Tl + (size_t)mg * WWE,
                D_, D_, blockIdx.x * 64, blockIdx.y * 64);
}

// ---------------------------------------------------------------------------
// Router post: sums 4 split-K partials + bias, LN, relu, logits, softmax, top2
// ---------------------------------------------------------------------------
__global__ __launch_bounds__(256) void router_post(
    const float* __restrict__ hpart, const float* __restrict__ br1,
    const float* __restrict__ ln_g, const float* __restrict__ ln_b,
    const float* __restrict__ Wr2, const float* __restrict__ br2,
    float* __restrict__ emask)
{
    const int t = blockIdx.x;
    const int tid = threadIdx.x;
    __shared__ float red[256];
    __shared__ float logits[E_];

    const float* hp = hpart + (size_t)t * D2_;
    float x0 = hp[tid] + hp[ND2 + tid] + hp[2 * ND2 + tid] + hp[3 * ND2 + tid] + br1[tid];
    float x1 = hp[tid + 256] + hp[ND2 + tid + 256] + hp[2 * ND2 + tid + 256]
             + hp[3 * ND2 + tid + 256] + br1[tid + 256];

    red[tid] = x0 + x1; __syncthreads();
    for (int off = 128; off; off >>= 1) { if (tid < off) red[tid] += red[tid + off]; __syncthreads(); }
    float mu = red[0] * (1.f / 512.f);
    __syncthreads();

    float d0 = x0 - mu, d1 = x1 - mu;
    red[tid] = d0 * d0 + d1 * d1; __syncthreads();
    for (int off = 128; off; off >>= 1) { if (tid < off) red[tid] += red[tid + off]; __syncthreads(); }
    float rs = rsqrtf(red[0] * (1.f / 512.f) + 1e-5f);
    __syncthreads();

    float n0 = fmaxf(fmaf(d0 * rs, ln_g[tid],       ln_b[tid]),       0.f);
    float n1 = fmaxf(fmaf(d1 * rs, ln_g[tid + 256], ln_b[tid + 256]), 0.f);

    for (int e = 0; e < E_; e++) {
        red[tid] = n0 * Wr2[(size_t)tid * E_ + e] + n1 * Wr2[(size_t)(tid + 256) * E_ + e];
        __syncthreads();
        for (int off = 128; off; off >>= 1) { if (tid < off) red[tid] += red[tid + off]; __syncthreads(); }
        if (tid == 0) logits[e] = red[0] + br2[e];
        __syncthreads();
    }

    if (tid == 0) {
        float mx = fmaxf(fmaxf(logits[0], logits[1]), fmaxf(logits[2], logits[3]));
        float p[E_], sum = 0.f;
        for (int e = 0; e < E_; e++) { p[e] = expf(logits[e] - mx); sum += p[e]; }
        float inv = 1.f / sum;
        for (int e = 0; e < E_; e++) p[e] *= inv;
        int i1 = 0;
        for (int e = 1; e < E_; e++) if (p[e] > p[i1]) i1 = e;
        int i2 = -1;
        for (int e = 0; e < E_; e++) { if (e == i1) continue; if (i2 < 0 || p[e] > p[i2]) i2 = e; }
        float o[E_] = {0.f, 0.f, 0.f, 0.f};
        o[i1] = p[i1]; o[i2] = p[i2];
        for (int e = 0; e < E_; e++) emask[(size_t)t * E_ + e] = o[e];
    }
}

// ---------------------------------------------------------------------------
extern "C" void kernel_launch(void* const* d_in, const int* in_sizes, int n_in,
                              void* d_out, int out_size, void* d_ws, size_t ws_size,
                              hipStream_t stream) {
    const float* x   = (const float*)d_in[0];
    const float* Wq  = (const float*)d_in[1];
    const float* bq  = (const float*)d_in[2];
    const float* Wk  = (const float*)d_in[3];
    const float* bk  = (const float*)d_in[4];
    const float* Wv  = (const float*)d_in[5];
    const float* bv  = (const float*)d_in[6];
    const float* Wo  = (const float*)d_in[7];
    const float* bo  = (const float*)d_in[8];
    const float* Wr1 = (const float*)d_in[9];
    const float* br1 = (const float*)d_in[10];
    const float* lng = (const float*)d_in[11];
    const float* lnb = (const float*)d_in[12];
    const float* Wr2 = (const float*)d_in[13];
    const float* br2 = (const float*)d_in[14];

    float* out = (float*)d_out;
    char* w = (char*)d_ws;
    dim3 blk(256);
    const size_t MB = 1024ull * 1024ull;

    // layout (~177 MB, proven available round 3)
    float*  emask = (float*)w;                          // 32 KB
    int*    idx   = (int*)(w + 64 * 1024);              // 32 KB
    int*    meta  = (int*)(w + 96 * 1024);              // 144 B
    ushort* wth   = (ushort*)(w + 1 * MB);              // 32 MB (16 mats)
    ushort* wtl   = (ushort*)(w + 33 * MB);
    char*   AC    = w + 65 * MB;                        // 32 MB region
    char*   BD    = AC + 32 * MB;                       // 80 MB region

    // region A (dead after projections / router_post)
    ushort* xh    = (ushort*)AC;                        // 4 MB
    ushort* xl    = (ushort*)(AC + 4 * MB);
    ushort* wr1h  = (ushort*)(AC + 8 * MB);             // 1 MB
    ushort* wr1l  = (ushort*)(AC + 9 * MB);
    float*  hpart = (float*)(AC + 10 * MB);             // 16 MB
    // region C (born at attn) aliases A
    ushort* ohb   = (ushort*)AC;                        // 16 MB
    ushort* olb   = (ushort*)(AC + 16 * MB);

    // region B (dead after attn)
    ushort* qhb   = (ushort*)BD;                        // 16 MB each
    ushort* qlb   = (ushort*)(BD + 16 * MB);
    ushort* khb   = (ushort*)(BD + 32 * MB);
    ushort* klb   = (ushort*)(BD + 48 * MB);
    ushort* vbb   = (ushort*)(BD + 64 * MB);
    // region D (born after attn) aliases B
    float*  out4  = (float*)BD;                         // 32 MB

    split_f32<<<dim3(NTOK * D_ / 1024), blk, 0, stream>>>(x, xh, xl);
    tsplit<<<dim3(D2_ / 64, D_ / 64), blk, 0, stream>>>(Wr1, wr1h, wr1l, D_, D2_);
    tsplit16<<<dim3(16, 16, 16), blk, 0, stream>>>(Wq, Wk, Wv, Wo, wth, wtl);

    gemm_router<<<dim3(D2_ / 128, NTOK / 128, 4), blk, 0, stream>>>(
        xh, xl, wr1h, wr1l, hpart);
    router_post<<<dim3(NTOK), blk, 0, stream>>>(hpart, br1, lng, lnb, Wr2, br2, emask);
    build_lists<<<dim3(E_), blk, 0, stream>>>(emask, idx, meta);

    gemm_kv_all<<<dim3(D_ / 128, NTOK / 128, 8), blk, 0, stream>>>(
        xh, xl, wth, wtl, bk, bv, khb, klb, vbb);
    gemm_q_gather<<<dim3(D_ / 128, NTOK / 128, 4), blk, 0, stream>>>(
        xh, xl, wth, wtl, bq, idx, meta, qhb, qlb);

    attn_all<<<dim3(S_ / 64, B_ * H_, E_), blk, 0, stream>>>(
        qhb, qlb, khb, klb, vbb, ohb, olb, meta);

    hipMemsetAsync(out4, 0, 4 * TDE * sizeof(float), stream);
    gemm_combine4<<<dim3(D_ / 128, NTOK / 128, 4), blk, 0, stream>>>(
        ohb, olb, wth, wtl, bo, emask, idx, meta, out4);
    reduce_out<<<dim3(TDE / 1024), blk, 0, stream>>>(out4, out);
}

// Round 5
// 343.931 us; speedup vs baseline: 1.0559x; 1.0559x over previous
//
#include <hip/hip_runtime.h>
#include <hip/hip_bf16.h>
#include <math.h>

#define B_   4
#define S_   512
#define D_   1024
#define H_   16
#define E_   4
#define HD_  64
#define D2_  512
#define NTOK (B_*S_)   // 2048

#define TDE ((size_t)NTOK * D_)   // elements of one [NTOK,D] buffer
#define WWE ((size_t)D_ * D_)     // elements of one [D,D] weight
#define ND2 ((size_t)NTOK * D2_)

typedef unsigned short ushort;
typedef short shortv8 __attribute__((ext_vector_type(8)));
typedef ushort ushortv8 __attribute__((ext_vector_type(8)));
typedef ushort ushortv4 __attribute__((ext_vector_type(4)));
typedef float floatv4 __attribute__((ext_vector_type(4)));

__device__ __forceinline__ ushort f2bf(float f) {
    union { __hip_bfloat16 b; ushort u; } cv;
    cv.b = __float2bfloat16(f);
    return cv.u;
}
__device__ __forceinline__ float bf2f(ushort u) {
    union { ushort u; __hip_bfloat16 b; } cv;
    cv.u = u;
    return __bfloat162float(cv.b);
}
__device__ __forceinline__ void splitbf(float v, ushort& hi, ushort& lo) {
    hi = f2bf(v);
    lo = f2bf(v - bf2f(hi));
}
__device__ __forceinline__ void gload16(const ushort* g, ushort* l) {
    __builtin_amdgcn_global_load_lds(
        (const __attribute__((address_space(1))) unsigned int*)g,
        (__attribute__((address_space(3))) unsigned int*)l, 16, 0, 0);
}

// ---------------------------------------------------------------------------
// Split-bf16 GEMM core, 2-phase prefetch w/ counted vmcnt (T3-min recipe).
// C = A @ Wt^T, A=[M][K] hi/lo, Wt=[N][K] hi/lo. 128x128 tile, BK=32,
// 4 waves, 3-term split. LDS: DOUBLE-buffered 4 tiles of 128x32 (2x32 KB).
// Per iter: STAGE(next buf) -> vmcnt(8) -> raw barrier -> ds_read+MFMA(cur)
// -> raw barrier. Loads for tile t+1 stay in flight through tile t's MFMAs.
// XOR chunk swizzle on global source + LDS read (involution, rule #21).
// GATHER=true: A rows taken from arow[] (bit31 = pad flag).
// ---------------------------------------------------------------------------
template<bool GATHER>
__device__ __forceinline__ void gemm_core_t(
    const ushort* __restrict__ A0, const ushort* __restrict__ A1,
    const ushort* __restrict__ B0, const ushort* __restrict__ B1,
    const int* __restrict__ arow,
    int K, int klen, int brow, int bcol, ushort* lds, floatv4 acc[4][4])
{
    const int tid  = threadIdx.x;
    const int wave = tid >> 6, lane = tid & 63;
    const int wm = wave >> 1, wn = wave & 1;
    const int lr = lane & 15, lc = lane >> 4;

    const ushort* gsrc[4] = {A0, A1, B0, B1};
    size_t goff[4][2];
    int    loff[4][2];
#pragma unroll
    for (int t = 0; t < 4; t++) {
#pragma unroll
        for (int s = 0; s < 2; s++) {
            int p = s * 256 + tid;
            int m = p >> 2;
            int c = (p & 3) ^ ((m >> 1) & 3);
            int r;
            if (t < 2) r = GATHER ? (arow[m] & 0x7FFFFFFF) : (brow + m);
            else       r = bcol + m;
            goff[t][s] = (size_t)r * K + c * 8;
            loff[t][s] = t * 4096 + p * 8;
        }
    }

    int aoff[4], boff[4];
#pragma unroll
    for (int i = 0; i < 4; i++) {
        int ra = wm * 64 + i * 16 + lr;
        aoff[i] = ra * 32 + ((lc ^ ((ra >> 1) & 3)) * 8);
        int rb2 = wn * 64 + i * 16 + lr;
        boff[i] = rb2 * 32 + ((lc ^ ((rb2 >> 1) & 3)) * 8);
    }

#define STAGE_(buf, kk) \
    _Pragma("unroll") for (int t = 0; t < 4; t++) \
    _Pragma("unroll") for (int s = 0; s < 2; s++) \
        gload16(gsrc[t] + goff[t][s] + (kk), lds + (buf) * 16384 + loff[t][s]);

    STAGE_(0, 0)

    int cur = 0;
    for (int k0 = 0; k0 < klen; k0 += 32, cur ^= 1) {
        if (k0 + 32 < klen) {
            STAGE_(cur ^ 1, k0 + 32)
            // previous tile's 8 DMAs done; this iter's 8 stay in flight
            asm volatile("s_waitcnt vmcnt(8)" ::: "memory");
        } else {
            asm volatile("s_waitcnt vmcnt(0)" ::: "memory");
        }
        __builtin_amdgcn_s_barrier();          // raw: no implicit vmcnt(0)
        __builtin_amdgcn_sched_barrier(0);     // rule #18: pin reads below

        const ushort* L = lds + cur * 16384;
        shortv8 ah[4], al[4], bh[4], bl[4];
#pragma unroll
        for (int i = 0; i < 4; i++) {
            ah[i] = *(const shortv8*)(L +         aoff[i]);
            al[i] = *(const shortv8*)(L +  4096 + aoff[i]);
            bh[i] = *(const shortv8*)(L +  8192 + boff[i]);
            bl[i] = *(const shortv8*)(L + 12288 + boff[i]);
        }
#pragma unroll
        for (int mi = 0; mi < 4; mi++)
#pragma unroll
            for (int nj = 0; nj < 4; nj++) {
                acc[mi][nj] = __builtin_amdgcn_mfma_f32_16x16x32_bf16(ah[mi], bh[nj], acc[mi][nj], 0, 0, 0);
                acc[mi][nj] = __builtin_amdgcn_mfma_f32_16x16x32_bf16(ah[mi], bl[nj], acc[mi][nj], 0, 0, 0);
                acc[mi][nj] = __builtin_amdgcn_mfma_f32_16x16x32_bf16(al[mi], bh[nj], acc[mi][nj], 0, 0, 0);
            }

        asm volatile("s_waitcnt lgkmcnt(0)" ::: "memory");  // reads complete
        __builtin_amdgcn_sched_barrier(0);
        __builtin_amdgcn_s_barrier();          // buf[cur] safe to overwrite
    }
#undef STAGE_
}

#define ACC_INIT(acc) \
    _Pragma("unroll") for (int i = 0; i < 4; i++) \
    _Pragma("unroll") for (int j = 0; j < 4; j++) \
    _Pragma("unroll") for (int q = 0; q < 4; q++) acc[i][j][q] = 0.f;

#define EPI_VARS \
    const int lane = threadIdx.x & 63, wave = threadIdx.x >> 6; \
    const int wm = wave >> 1, wn = wave & 1, lr = lane & 15, lc = lane >> 4;

// ---- Router hidden GEMM, split-K x4 ----
__global__ __launch_bounds__(256, 2) void gemm_router(
    const ushort* __restrict__ xh, const ushort* __restrict__ xl,
    const ushort* __restrict__ wr1h, const ushort* __restrict__ wr1l,
    float* __restrict__ hpart)
{
    __shared__ ushort lds[32768];
    floatv4 acc[4][4];
    ACC_INIT(acc)

    const int kz = blockIdx.z;
    const int koff = kz * 256;
    const int brow = blockIdx.y * 128, bcol = blockIdx.x * 128;
    gemm_core_t<false>(xh + koff, xl + koff, wr1h + koff, wr1l + koff,
                       nullptr, D_, 256, brow, bcol, lds, acc);

    float* C = hpart + (size_t)kz * ND2;
    EPI_VARS
#pragma unroll
    for (int mi = 0; mi < 4; mi++)
#pragma unroll
        for (int nj = 0; nj < 4; nj++)
#pragma unroll
            for (int i = 0; i < 4; i++) {
                int row = brow + wm * 64 + mi * 16 + lc * 4 + i;
                int col = bcol + wn * 64 + nj * 16 + lr;
                C[(size_t)row * D2_ + col] = acc[mi][nj][i];
            }
}

// ---- Fused projections: z 0..7 = dense K/V (slot=z>>1, m=z&1),
//      z 8..11 = gathered Q (expert = z-8, compacted rows) ----
__global__ __launch_bounds__(256, 2) void gemm_proj(
    const ushort* __restrict__ xh, const ushort* __restrict__ xl,
    const ushort* __restrict__ wth, const ushort* __restrict__ wtl,
    const float* __restrict__ bq, const float* __restrict__ bk, const float* __restrict__ bv,
    const int* __restrict__ idx, const int* __restrict__ meta,
    ushort* __restrict__ qh, ushort* __restrict__ ql,
    ushort* __restrict__ kh, ushort* __restrict__ kl, ushort* __restrict__ vb)
{
    __shared__ ushort lds[32768];
    const int z = blockIdx.z;
    const int brow = blockIdx.y * 128, bcol = blockIdx.x * 128;

    if (z < 8) {
        const int slot = z >> 1, m = z & 1;
        const size_t so = (size_t)slot * TDE;
        const ushort* Bh = wth + (size_t)(slot * 4 + 1 + m) * WWE;   // 1=K, 2=V
        const ushort* Bl = wtl + (size_t)(slot * 4 + 1 + m) * WWE;
        const float* bias = ((m == 0) ? bk : bv) + (size_t)slot * D_;
        ushort* Oh = ((m == 0) ? kh : vb) + so;
        ushort* Ol = (m == 0) ? kl + so : nullptr;

        floatv4 acc[4][4];
        ACC_INIT(acc)
        gemm_core_t<false>(xh, xl, Bh, Bl, nullptr, D_, D_, brow, bcol, lds, acc);

        EPI_VARS
#pragma unroll
        for (int mi = 0; mi < 4; mi++)
#pragma unroll
            for (int nj = 0; nj < 4; nj++)
#pragma unroll
                for (int i = 0; i < 4; i++) {
                    int row = brow + wm * 64 + mi * 16 + lc * 4 + i;
                    int col = bcol + wn * 64 + nj * 16 + lr;
                    float val = acc[mi][nj][i] + bias[col];
                    ushort h = f2bf(val);
                    Oh[(size_t)row * D_ + col] = h;
                    if (Ol) Ol[(size_t)row * D_ + col] = f2bf(val - bf2f(h));
                }
    } else {
        const int e = z - 8;
        const int pcnt = meta[32 + e];
        if (brow >= pcnt) return;
        const int* arow = idx + e * 2048 + brow;
        const ushort* Bh = wth + (size_t)(e * 4 + 0) * WWE;
        const ushort* Bl = wtl + (size_t)(e * 4 + 0) * WWE;
        const float* bias = bq + (size_t)e * D_;
        const size_t so = (size_t)e * TDE;

        floatv4 acc[4][4];
        ACC_INIT(acc)
        gemm_core_t<true>(xh, xl, Bh, Bl, arow, D_, D_, brow, bcol, lds, acc);

        EPI_VARS
#pragma unroll
        for (int mi = 0; mi < 4; mi++)
#pragma unroll
            for (int nj = 0; nj < 4; nj++)
#pragma unroll
                for (int i = 0; i < 4; i++) {
                    int row = brow + wm * 64 + mi * 16 + lc * 4 + i;   // slot
                    int col = bcol + wn * 64 + nj * 16 + lr;
                    float val = (acc[mi][nj][i] + bias[col]) * 0.125f;
                    ushort h = f2bf(val);
                    qh[so + (size_t)row * D_ + col] = h;
                    ql[so + (size_t)row * D_ + col] = f2bf(val - bf2f(h));
                }
    }
}

// ---- Output projection on compacted rows + scatter into out4 slice ----
__global__ __launch_bounds__(256, 2) void gemm_combine4(
    const ushort* __restrict__ oh, const ushort* __restrict__ ol,
    const ushort* __restrict__ wth, const ushort* __restrict__ wtl,
    const float* __restrict__ bo, const float* __restrict__ emask,
    const int* __restrict__ idx, const int* __restrict__ meta,
    float* __restrict__ out4)
{
    __shared__ ushort lds[32768];
    const int e = blockIdx.z;
    const int pcnt = meta[32 + e];
    const int brow = blockIdx.y * 128;
    if (brow >= pcnt) return;
    const int bcol = blockIdx.x * 128;
    const size_t so = (size_t)e * TDE;
    const ushort* Bh = wth + (size_t)(e * 4 + 3) * WWE;
    const ushort* Bl = wtl + (size_t)(e * 4 + 3) * WWE;
    const float* bias = bo + (size_t)e * D_;
    const int* idxe = idx + e * 2048;

    floatv4 acc[4][4];
    ACC_INIT(acc)
    gemm_core_t<false>(oh + so, ol + so, Bh, Bl, nullptr, D_, D_, brow, bcol, lds, acc);

    float* dst = out4 + so;
    EPI_VARS
#pragma unroll
    for (int mi = 0; mi < 4; mi++)
#pragma unroll
        for (int nj = 0; nj < 4; nj++)
#pragma unroll
            for (int i = 0; i < 4; i++) {
                int srow = brow + wm * 64 + mi * 16 + lc * 4 + i;
                int raw = idxe[srow];
                if (raw >= 0) {   // bit31 = pad flag
                    float s = emask[(size_t)raw * E_ + e];
                    int col = bcol + wn * 64 + nj * 16 + lr;
                    dst[(size_t)raw * D_ + col] = s * (acc[mi][nj][i] + bias[col]);
                }
            }
}

// ---- reduce out4 slices -> out ----
__global__ __launch_bounds__(256) void reduce_out(
    const float* __restrict__ out4, float* __restrict__ out)
{
    size_t i = (size_t)blockIdx.x * 256 + threadIdx.x;
    const float4* p = (const float4*)out4;
    float4 a = p[i], b = p[i + TDE / 4], c = p[i + 2 * (TDE / 4)], d = p[i + 3 * (TDE / 4)];
    float4 r;
    r.x = a.x + b.x + c.x + d.x;
    r.y = a.y + b.y + c.y + d.y;
    r.z = a.z + b.z + c.z + d.z;
    r.w = a.w + b.w + c.w + d.w;
    ((float4*)out)[i] = r;
}

// ---------------------------------------------------------------------------
// Per-(expert,batch) routed-token lists, 64-padded, deterministic order.
// ---------------------------------------------------------------------------
__global__ __launch_bounds__(256) void build_lists(
    const float* __restrict__ emask, int* __restrict__ idx, int* __restrict__ meta)
{
    const int e = blockIdx.x;
    const int tid = threadIdx.x;
    __shared__ int scan[256];
    __shared__ int runsh;
    if (tid == 0) runsh = 0;
    int* idxe = idx + e * 2048;

    for (int b = 0; b < B_; b++) {
        __syncthreads();
        const int base = runsh;
        int t0 = b * 512 + tid * 2;
        int f0 = (emask[(size_t)t0 * E_ + e] != 0.f) ? 1 : 0;
        int f1 = (emask[(size_t)(t0 + 1) * E_ + e] != 0.f) ? 1 : 0;
        int my = f0 + f1;
        scan[tid] = my;
        __syncthreads();
        for (int off = 1; off < 256; off <<= 1) {
            int v = (tid >= off) ? scan[tid - off] : 0;
            __syncthreads();
            scan[tid] += v;
            __syncthreads();
        }
        int excl = scan[tid] - my;
        int cnt = scan[255];
        if (f0) idxe[base + excl] = t0;
        if (f1) idxe[base + excl + f0] = t0 + 1;
        int plen = (cnt + 63) & ~63;
        for (int i = cnt + tid; i < plen; i += 256)
            idxe[base + i] = (b * 512) | (int)0x80000000;
        if (tid == 0) {
            meta[e * 4 + b] = base;
            meta[16 + e * 4 + b] = plen >> 6;
            runsh = base + plen;
        }
    }
    __syncthreads();
    int total = runsh;
    if (tid == 0) meta[32 + e] = total;
    for (int i = total + tid; i < 2048; i += 256)
        idxe[i] = (int)0x80000000;
}

// ---------------------------------------------------------------------------
// MFMA flash attention on compacted Q rows (validated r4).
// ---------------------------------------------------------------------------
__global__ __launch_bounds__(256, 2) void attn_all(
    const ushort* __restrict__ qh_, const ushort* __restrict__ ql_,
    const ushort* __restrict__ kh_, const ushort* __restrict__ kl_,
    const ushort* __restrict__ vv_,
    ushort* __restrict__ oh_, ushort* __restrict__ ol_,
    const int* __restrict__ meta)
{
    const int e = blockIdx.z;
    const int bhid = blockIdx.y, bb = bhid >> 4, hh = bhid & 15;
    const int ptiles = meta[16 + e * 4 + bb];
    if ((int)blockIdx.x >= ptiles) return;
    const int pstart = meta[e * 4 + bb];

    __shared__ ushort Kh[4096], Kl[4096];
    __shared__ ushort Vt[64 * 72];
    __shared__ ushort Pw[4][16 * 72];

    const size_t zo = (size_t)e * TDE;
    const int tid = threadIdx.x;
    const int wave = tid >> 6, lane = tid & 63;
    const int lr = lane & 15, lc = lane >> 4;
    const int q0 = pstart + blockIdx.x * 64;
    const size_t kvbase = zo + (size_t)bb * S_ * D_ + hh * 64;
    const size_t qobase = zo + hh * 64;

    shortv8 qfh[2], qfl[2];
    {
        size_t qoff = qobase + (size_t)(q0 + wave * 16 + lr) * D_ + lc * 8;
        qfh[0] = *(const shortv8*)(qh_ + qoff);
        qfh[1] = *(const shortv8*)(qh_ + qoff + 32);
        qfl[0] = *(const shortv8*)(ql_ + qoff);
        qfl[1] = *(const shortv8*)(ql_ + qoff + 32);
    }

    floatv4 ov[4];
    float m4[4], l4[4];
#pragma unroll
    for (int df = 0; df < 4; df++)
#pragma unroll
        for (int i = 0; i < 4; i++) ov[df][i] = 0.f;
#pragma unroll
    for (int i = 0; i < 4; i++) { m4[i] = -3.0e38f; l4[i] = 0.f; }

    for (int kt = 0; kt < S_ / 64; kt++) {
        const int kk0 = kt * 64;
        __syncthreads();

#pragma unroll
        for (int t = 0; t < 2; t++) {
            const ushort* src = t ? kl_ : kh_;
            ushort* dst = t ? Kl : Kh;
#pragma unroll
            for (int s = 0; s < 2; s++) {
                int p = s * 256 + tid;
                int r = p >> 3;
                int c = (p & 7) ^ (r & 7);
                gload16(src + kvbase + (size_t)(kk0 + r) * D_ + c * 8, dst + p * 8);
            }
        }
        {
            const ushort* vsrc = vv_ + kvbase + (size_t)(kk0 + lane) * D_ + wave * 16;
            ushortv8 v0 = *(const ushortv8*)vsrc;
            ushortv8 v1 = *(const ushortv8*)(vsrc + 8);
#pragma unroll
            for (int j = 0; j < 8; j++) Vt[(wave * 16 + j) * 72 + lane] = v0[j];
#pragma unroll
            for (int j = 0; j < 8; j++) Vt[(wave * 16 + 8 + j) * 72 + lane] = v1[j];
        }
        __syncthreads();

        floatv4 sc[4];
#pragma unroll
        for (int n = 0; n < 4; n++)
#pragma unroll
            for (int i = 0; i < 4; i++) sc[n][i] = 0.f;
#pragma unroll
        for (int n = 0; n < 4; n++)
#pragma unroll
            for (int ds = 0; ds < 2; ds++) {
                int off = (16 * n + lr) * 64 + (((ds * 4 + lc) ^ (lr & 7)) * 8);
                shortv8 kfh = *(const shortv8*)(Kh + off);
                shortv8 kfl = *(const shortv8*)(Kl + off);
                sc[n] = __builtin_amdgcn_mfma_f32_16x16x32_bf16(qfh[ds], kfh, sc[n], 0, 0, 0);
                sc[n] = __builtin_amdgcn_mfma_f32_16x16x32_bf16(qfh[ds], kfl, sc[n], 0, 0, 0);
                sc[n] = __builtin_amdgcn_mfma_f32_16x16x32_bf16(qfl[ds], kfh, sc[n], 0, 0, 0);
            }

        float tm[4];
#pragma unroll
        for (int i = 0; i < 4; i++)
            tm[i] = fmaxf(fmaxf(sc[0][i], sc[1][i]), fmaxf(sc[2][i], sc[3][i]));
#pragma unroll
        for (int off = 1; off <= 8; off <<= 1)
#pragma unroll
            for (int i = 0; i < 4; i++)
                tm[i] = fmaxf(tm[i], __shfl_xor(tm[i], off));

        float nm[4], sca[4], ps[4];
#pragma unroll
        for (int i = 0; i < 4; i++) {
            nm[i] = fmaxf(m4[i], tm[i]);
            sca[i] = __expf(m4[i] - nm[i]);
            ps[i] = 0.f;
        }
        float pval[4][4];
#pragma unroll
        for (int n = 0; n < 4; n++)
#pragma unroll
            for (int i = 0; i < 4; i++) {
                float p = __expf(sc[n][i] - nm[i]);
                pval[n][i] = p;
                ps[i] += p;
            }
#pragma unroll
        for (int off = 1; off <= 8; off <<= 1)
#pragma unroll
            for (int i = 0; i < 4; i++)
                ps[i] += __shfl_xor(ps[i], off);
#pragma unroll
        for (int i = 0; i < 4; i++) {
            l4[i] = l4[i] * sca[i] + ps[i];
            m4[i] = nm[i];
        }
#pragma unroll
        for (int df = 0; df < 4; df++)
#pragma unroll
            for (int i = 0; i < 4; i++) ov[df][i] *= sca[i];

#pragma unroll
        for (int n = 0; n < 4; n++)
#pragma unroll
            for (int i = 0; i < 4; i++)
                Pw[wave][(lc * 4 + i) * 72 + 16 * n + lr] = f2bf(pval[n][i]);
        __syncthreads();

#pragma unroll
        for (int ks = 0; ks < 2; ks++) {
            shortv8 pa = *(const shortv8*)(&Pw[wave][lr * 72 + ks * 32 + lc * 8]);
#pragma unroll
            for (int df = 0; df < 4; df++) {
                shortv8 vf = *(const shortv8*)(Vt + (df * 16 + lr) * 72 + ks * 32 + lc * 8);
                ov[df] = __builtin_amdgcn_mfma_f32_16x16x32_bf16(pa, vf, ov[df], 0, 0, 0);
            }
        }
    }

#pragma unroll
    for (int df = 0; df < 4; df++)
#pragma unroll
        for (int i = 0; i < 4; i++) {
            float val = ov[df][i] / l4[i];
            size_t off = qobase + (size_t)(q0 + wave * 16 + lc * 4 + i) * D_ + df * 16 + lr;
            ushort h, l;
            splitbf(val, h, l);
            oh_[off] = h;
            ol_[off] = l;
        }
}

// ---------------------------------------------------------------------------
__global__ __launch_bounds__(256) void split_f32(
    const float* __restrict__ in, ushort* __restrict__ hi, ushort* __restrict__ lo)
{
    int i = blockIdx.x * 256 + threadIdx.x;
    float4 v = ((const float4*)in)[i];
    ushortv4 hv, lv;
    ushort h, l;
    splitbf(v.x, h, l); hv[0] = h; lv[0] = l;
    splitbf(v.y, h, l); hv[1] = h; lv[1] = l;
    splitbf(v.z, h, l); hv[2] = h; lv[2] = l;
    splitbf(v.w, h, l); hv[3] = h; lv[3] = l;
    ((ushortv4*)hi)[i] = hv;
    ((ushortv4*)lo)[i] = lv;
}

// ---------------------------------------------------------------------------
// Transpose + split: W[K][N] fp32 -> Th/Tl[N][K] bf16. 64x64 tiles.
// ---------------------------------------------------------------------------
__device__ __forceinline__ void tsplit_body(
    const float* __restrict__ W, ushort* __restrict__ Th, ushort* __restrict__ Tl,
    int K, int N, int n0, int k0)
{
    __shared__ float tile[64][65];
    const int tid = threadIdx.x;
#pragma unroll
    for (int i = 0; i < 16; i++) {
        int idx = i * 256 + tid;
        int r = idx >> 6, c = idx & 63;
        tile[r][c] = W[(size_t)(k0 + r) * N + n0 + c];
    }
    __syncthreads();
#pragma unroll
    for (int i = 0; i < 16; i++) {
        int idx = i * 256 + tid;
        int rn = idx >> 6, ck = idx & 63;
        float v = tile[ck][rn];
        ushort h, l;
        splitbf(v, h, l);
        Th[(size_t)(n0 + rn) * K + k0 + ck] = h;
        Tl[(size_t)(n0 + rn) * K + k0 + ck] = l;
    }
}

__global__ __launch_bounds__(256) void tsplit(
    const float* __restrict__ W, ushort* __restrict__ Th, ushort* __restrict__ Tl,
    int K, int N)
{
    tsplit_body(W, Th, Tl, K, N, blockIdx.x * 64, blockIdx.y * 64);
}

__global__ __launch_bounds__(256) void tsplit16(
    const float* __restrict__ Wq, const float* __restrict__ Wk,
    const float* __restrict__ Wv, const float* __restrict__ Wo,
    ushort* __restrict__ Th, ushort* __restrict__ Tl)
{
    const int mg = blockIdx.z;
    const int e = mg >> 2, m = mg & 3;
    const float* W = ((m == 0) ? Wq : (m == 1) ? Wk : (m == 2) ? Wv : Wo) + (size_t)e * WWE;
    tsplit_body(W, Th + (size_t)mg * WWE, Tl + (size_t)mg * WWE,
                D_, D_, blockIdx.x * 64, blockIdx.y * 64);
}

// ---------------------------------------------------------------------------
// Router post: sums 4 split-K partials + bias, LN, relu, logits, softmax, top2
// ---------------------------------------------------------------------------
__global__ __launch_bounds__(256) void router_post(
    const float* __restrict__ hpart, const float* __restrict__ br1,
    const float* __restrict__ ln_g, const float* __restrict__ ln_b,
    const float* __restrict__ Wr2, const float* __restrict__ br2,
    float* __restrict__ emask)
{
    const int t = blockIdx.x;
    const int tid = threadIdx.x;
    __shared__ float red[256];
    __shared__ float logits[E_];

    const float* hp = hpart + (size_t)t * D2_;
    float x0 = hp[tid] + hp[ND2 + tid] + hp[2 * ND2 + tid] + hp[3 * ND2 + tid] + br1[tid];
    float x1 = hp[tid + 256] + hp[ND2 + tid + 256] + hp[2 * ND2 + tid + 256]
             + hp[3 * ND2 + tid + 256] + br1[tid + 256];

    red[tid] = x0 + x1; __syncthreads();
    for (int off = 128; off; off >>= 1) { if (tid < off) red[tid] += red[tid + off]; __syncthreads(); }
    float mu = red[0] * (1.f / 512.f);
    __syncthreads();

    float d0 = x0 - mu, d1 = x1 - mu;
    red[tid] = d0 * d0 + d1 * d1; __syncthreads();
    for (int off = 128; off; off >>= 1) { if (tid < off) red[tid] += red[tid + off]; __syncthreads(); }
    float rs = rsqrtf(red[0] * (1.f / 512.f) + 1e-5f);
    __syncthreads();

    float n0 = fmaxf(fmaf(d0 * rs, ln_g[tid],       ln_b[tid]),       0.f);
    float n1 = fmaxf(fmaf(d1 * rs, ln_g[tid + 256], ln_b[tid + 256]), 0.f);

    for (int e = 0; e < E_; e++) {
        red[tid] = n0 * Wr2[(size_t)tid * E_ + e] + n1 * Wr2[(size_t)(tid + 256) * E_ + e];
        __syncthreads();
        for (int off = 128; off; off >>= 1) { if (tid < off) red[tid] += red[tid + off]; __syncthreads(); }
        if (tid == 0) logits[e] = red[0] + br2[e];
        __syncthreads();
    }

    if (tid == 0) {
        float mx = fmaxf(fmaxf(logits[0], logits[1]), fmaxf(logits[2], logits[3]));
        float p[E_], sum = 0.f;
        for (int e = 0; e < E_; e++) { p[e] = expf(logits[e] - mx); sum += p[e]; }
        float inv = 1.f / sum;
        for (int e = 0; e < E_; e++) p[e] *= inv;
        int i1 = 0;
        for (int e = 1; e < E_; e++) if (p[e] > p[i1]) i1 = e;
        int i2 = -1;
        for (int e = 0; e < E_; e++) { if (e == i1) continue; if (i2 < 0 || p[e] > p[i2]) i2 = e; }
        float o[E_] = {0.f, 0.f, 0.f, 0.f};
        o[i1] = p[i1]; o[i2] = p[i2];
        for (int e = 0; e < E_; e++) emask[(size_t)t * E_ + e] = o[e];
    }
}

// ---------------------------------------------------------------------------
extern "C" void kernel_launch(void* const* d_in, const int* in_sizes, int n_in,
                              void* d_out, int out_size, void* d_ws, size_t ws_size,
                              hipStream_t stream) {
    const float* x   = (const float*)d_in[0];
    const float* Wq  = (const float*)d_in[1];
    const float* bq  = (const float*)d_in[2];
    const float* Wk  = (const float*)d_in[3];
    const float* bk  = (const float*)d_in[4];
    const float* Wv  = (const float*)d_in[5];
    const float* bv  = (const float*)d_in[6];
    const float* Wo  = (const float*)d_in[7];
    const float* bo  = (const float*)d_in[8];
    const float* Wr1 = (const float*)d_in[9];
    const float* br1 = (const float*)d_in[10];
    const float* lng = (const float*)d_in[11];
    const float* lnb = (const float*)d_in[12];
    const float* Wr2 = (const float*)d_in[13];
    const float* br2 = (const float*)d_in[14];

    float* out = (float*)d_out;
    char* w = (char*)d_ws;
    dim3 blk(256);
    const size_t MB = 1024ull * 1024ull;

    float*  emask = (float*)w;                          // 32 KB
    int*    idx   = (int*)(w + 64 * 1024);              // 32 KB
    int*    meta  = (int*)(w + 96 * 1024);              // 144 B
    ushort* wth   = (ushort*)(w + 1 * MB);              // 32 MB (16 mats)
    ushort* wtl   = (ushort*)(w + 33 * MB);
    char*   AC    = w + 65 * MB;                        // 32 MB region
    char*   BD    = AC + 32 * MB;                       // 80 MB region

    // region A (dead after projections / router_post)
    ushort* xh    = (ushort*)AC;                        // 4 MB
    ushort* xl    = (ushort*)(AC + 4 * MB);
    ushort* wr1h  = (ushort*)(AC + 8 * MB);             // 1 MB
    ushort* wr1l  = (ushort*)(AC + 9 * MB);
    float*  hpart = (float*)(AC + 10 * MB);             // 16 MB
    // region C (born at attn) aliases A
    ushort* ohb   = (ushort*)AC;                        // 16 MB
    ushort* olb   = (ushort*)(AC + 16 * MB);

    // region B (dead after attn)
    ushort* qhb   = (ushort*)BD;                        // 16 MB each
    ushort* qlb   = (ushort*)(BD + 16 * MB);
    ushort* khb   = (ushort*)(BD + 32 * MB);
    ushort* klb   = (ushort*)(BD + 48 * MB);
    ushort* vbb   = (ushort*)(BD + 64 * MB);
    // region D (born after attn) aliases B
    float*  out4  = (float*)BD;                         // 32 MB

    split_f32<<<dim3(NTOK * D_ / 1024), blk, 0, stream>>>(x, xh, xl);
    tsplit<<<dim3(D2_ / 64, D_ / 64), blk, 0, stream>>>(Wr1, wr1h, wr1l, D_, D2_);
    tsplit16<<<dim3(16, 16, 16), blk, 0, stream>>>(Wq, Wk, Wv, Wo, wth, wtl);

    gemm_router<<<dim3(D2_ / 128, NTOK / 128, 4), blk, 0, stream>>>(
        xh, xl, wr1h, wr1l, hpart);
    router_post<<<dim3(NTOK), blk, 0, stream>>>(hpart, br1, lng, lnb, Wr2, br2, emask);
    build_lists<<<dim3(E_), blk, 0, stream>>>(emask, idx, meta);

    gemm_proj<<<dim3(D_ / 128, NTOK / 128, 12), blk, 0, stream>>>(
        xh, xl, wth, wtl, bq, bk, bv, idx, meta, qhb, qlb, khb, klb, vbb);

    attn_all<<<dim3(S_ / 64, B_ * H_, E_), blk, 0, stream>>>(
        qhb, qlb, khb, klb, vbb, ohb, olb, meta);

    hipMemsetAsync(out4, 0, 4 * TDE * sizeof(float), stream);
    gemm_combine4<<<dim3(D_ / 128, NTOK / 128, 4), blk, 0, stream>>>(
        ohb, olb, wth, wtl, bo, emask, idx, meta, out4);
    reduce_out<<<dim3(TDE / 1024), blk, 0, stream>>>(out4, out);
}

// Round 6
// 282.342 us; speedup vs baseline: 1.2863x; 1.2181x over previous
//
#include <hip/hip_runtime.h>
#include <hip/hip_bf16.h>
#include <math.h>

#define B_   4
#define S_   512
#define D_   1024
#define H_   16
#define E_   4
#define HD_  64
#define D2_  512
#define NTOK (B_*S_)   // 2048

#define TDE ((size_t)NTOK * D_)   // elements of one [NTOK,D] buffer
#define WWE ((size_t)D_ * D_)     // elements of one [D,D] weight
#define ND2 ((size_t)NTOK * D2_)

typedef unsigned short ushort;
typedef short shortv8 __attribute__((ext_vector_type(8)));
typedef ushort ushortv4 __attribute__((ext_vector_type(4)));
typedef _Float16 halfv8 __attribute__((ext_vector_type(8)));
typedef _Float16 halfv4 __attribute__((ext_vector_type(4)));
typedef float floatv4 __attribute__((ext_vector_type(4)));

__device__ __forceinline__ ushort f2bf(float f) {
    union { __hip_bfloat16 b; ushort u; } cv;
    cv.b = __float2bfloat16(f);
    return cv.u;
}
__device__ __forceinline__ float bf2f(ushort u) {
    union { ushort u; __hip_bfloat16 b; } cv;
    cv.u = u;
    return __bfloat162float(cv.b);
}
__device__ __forceinline__ void gload16(const void* g, void* l) {
    __builtin_amdgcn_global_load_lds(
        (const __attribute__((address_space(1))) unsigned int*)g,
        (__attribute__((address_space(3))) unsigned int*)l, 16, 0, 0);
}

// ---------------------------------------------------------------------------
// bf16 split 3-term GEMM core — ROUTER ONLY (validated r2-r5, numerics frozen
// so top-2 expert decisions never flip). 2-phase prefetch, counted vmcnt(8).
// ---------------------------------------------------------------------------
__device__ __forceinline__ void gemm_core_bf(
    const ushort* __restrict__ A0, const ushort* __restrict__ A1,
    const ushort* __restrict__ B0, const ushort* __restrict__ B1,
    int K, int klen, int brow, int bcol, ushort* lds, floatv4 acc[4][4])
{
    const int tid  = threadIdx.x;
    const int wave = tid >> 6, lane = tid & 63;
    const int wm = wave >> 1, wn = wave & 1;
    const int lr = lane & 15, lc = lane >> 4;

    const ushort* gsrc[4] = {A0, A1, B0, B1};
    size_t goff[4][2];
    int    loff[4][2];
#pragma unroll
    for (int t = 0; t < 4; t++) {
#pragma unroll
        for (int s = 0; s < 2; s++) {
            int p = s * 256 + tid;
            int m = p >> 2;
            int c = (p & 3) ^ ((m >> 1) & 3);
            int r = (t < 2) ? (brow + m) : (bcol + m);
            goff[t][s] = (size_t)r * K + c * 8;
            loff[t][s] = t * 4096 + p * 8;
        }
    }

    int aoff[4], boff[4];
#pragma unroll
    for (int i = 0; i < 4; i++) {
        int ra = wm * 64 + i * 16 + lr;
        aoff[i] = ra * 32 + ((lc ^ ((ra >> 1) & 3)) * 8);
        int rb2 = wn * 64 + i * 16 + lr;
        boff[i] = rb2 * 32 + ((lc ^ ((rb2 >> 1) & 3)) * 8);
    }

#define STAGEB_(buf, kk) \
    _Pragma("unroll") for (int t = 0; t < 4; t++) \
    _Pragma("unroll") for (int s = 0; s < 2; s++) \
        gload16(gsrc[t] + goff[t][s] + (kk), lds + (buf) * 16384 + loff[t][s]);

    STAGEB_(0, 0)

    int cur = 0;
    for (int k0 = 0; k0 < klen; k0 += 32, cur ^= 1) {
        if (k0 + 32 < klen) {
            STAGEB_(cur ^ 1, k0 + 32)
            asm volatile("s_waitcnt vmcnt(8)" ::: "memory");
        } else {
            asm volatile("s_waitcnt vmcnt(0)" ::: "memory");
        }
        __builtin_amdgcn_s_barrier();
        __builtin_amdgcn_sched_barrier(0);

        const ushort* L = lds + cur * 16384;
        shortv8 ah[4], al[4], bh[4], bl[4];
#pragma unroll
        for (int i = 0; i < 4; i++) {
            ah[i] = *(const shortv8*)(L +         aoff[i]);
            al[i] = *(const shortv8*)(L +  4096 + aoff[i]);
            bh[i] = *(const shortv8*)(L +  8192 + boff[i]);
            bl[i] = *(const shortv8*)(L + 12288 + boff[i]);
        }
#pragma unroll
        for (int mi = 0; mi < 4; mi++)
#pragma unroll
            for (int nj = 0; nj < 4; nj++) {
                acc[mi][nj] = __builtin_amdgcn_mfma_f32_16x16x32_bf16(ah[mi], bh[nj], acc[mi][nj], 0, 0, 0);
                acc[mi][nj] = __builtin_amdgcn_mfma_f32_16x16x32_bf16(ah[mi], bl[nj], acc[mi][nj], 0, 0, 0);
                acc[mi][nj] = __builtin_amdgcn_mfma_f32_16x16x32_bf16(al[mi], bh[nj], acc[mi][nj], 0, 0, 0);
            }

        asm volatile("s_waitcnt lgkmcnt(0)" ::: "memory");
        __builtin_amdgcn_sched_barrier(0);
        __builtin_amdgcn_s_barrier();
    }
#undef STAGEB_
}

// ---------------------------------------------------------------------------
// fp16 2-term GEMM core (A-split): C = (Ah+Al) @ W^T, W single fp16.
// Same validated 2-phase sync structure, 3 staged tiles, counted vmcnt(6).
// GATHER=true: A rows from arow[] (bit31 = pad flag).
// ---------------------------------------------------------------------------
template<bool GATHER>
__device__ __forceinline__ void gemm_core_h(
    const _Float16* __restrict__ A0, const _Float16* __restrict__ A1,
    const _Float16* __restrict__ B0,
    const int* __restrict__ arow,
    int K, int klen, int brow, int bcol, _Float16* lds, floatv4 acc[4][4])
{
    const int tid  = threadIdx.x;
    const int wave = tid >> 6, lane = tid & 63;
    const int wm = wave >> 1, wn = wave & 1;
    const int lr = lane & 15, lc = lane >> 4;

    const _Float16* gsrc[3] = {A0, A1, B0};
    size_t goff[3][2];
    int    loff[3][2];
#pragma unroll
    for (int t = 0; t < 3; t++) {
#pragma unroll
        for (int s = 0; s < 2; s++) {
            int p = s * 256 + tid;
            int m = p >> 2;
            int c = (p & 3) ^ ((m >> 1) & 3);
            int r;
            if (t < 2) r = GATHER ? (arow[m] & 0x7FFFFFFF) : (brow + m);
            else       r = bcol + m;
            goff[t][s] = (size_t)r * K + c * 8;
            loff[t][s] = t * 4096 + p * 8;
        }
    }

    int aoff[4], boff[4];
#pragma unroll
    for (int i = 0; i < 4; i++) {
        int ra = wm * 64 + i * 16 + lr;
        aoff[i] = ra * 32 + ((lc ^ ((ra >> 1) & 3)) * 8);
        int rb2 = wn * 64 + i * 16 + lr;
        boff[i] = rb2 * 32 + ((lc ^ ((rb2 >> 1) & 3)) * 8);
    }

#define STAGEH_(buf, kk) \
    _Pragma("unroll") for (int t = 0; t < 3; t++) \
    _Pragma("unroll") for (int s = 0; s < 2; s++) \
        gload16(gsrc[t] + goff[t][s] + (kk), lds + (buf) * 12288 + loff[t][s]);

    STAGEH_(0, 0)

    int cur = 0;
    for (int k0 = 0; k0 < klen; k0 += 32, cur ^= 1) {
        if (k0 + 32 < klen) {
            STAGEH_(cur ^ 1, k0 + 32)
            asm volatile("s_waitcnt vmcnt(6)" ::: "memory");
        } else {
            asm volatile("s_waitcnt vmcnt(0)" ::: "memory");
        }
        __builtin_amdgcn_s_barrier();
        __builtin_amdgcn_sched_barrier(0);

        const _Float16* L = lds + cur * 12288;
        halfv8 ah[4], al[4], bb[4];
#pragma unroll
        for (int i = 0; i < 4; i++) {
            ah[i] = *(const halfv8*)(L +        aoff[i]);
            al[i] = *(const halfv8*)(L + 4096 + aoff[i]);
            bb[i] = *(const halfv8*)(L + 8192 + boff[i]);
        }
#pragma unroll
        for (int mi = 0; mi < 4; mi++)
#pragma unroll
            for (int nj = 0; nj < 4; nj++) {
                acc[mi][nj] = __builtin_amdgcn_mfma_f32_16x16x32_f16(ah[mi], bb[nj], acc[mi][nj], 0, 0, 0);
                acc[mi][nj] = __builtin_amdgcn_mfma_f32_16x16x32_f16(al[mi], bb[nj], acc[mi][nj], 0, 0, 0);
            }

        asm volatile("s_waitcnt lgkmcnt(0)" ::: "memory");
        __builtin_amdgcn_sched_barrier(0);
        __builtin_amdgcn_s_barrier();
    }
#undef STAGEH_
}

#define ACC_INIT(acc) \
    _Pragma("unroll") for (int i = 0; i < 4; i++) \
    _Pragma("unroll") for (int j = 0; j < 4; j++) \
    _Pragma("unroll") for (int q = 0; q < 4; q++) acc[i][j][q] = 0.f;

#define EPI_VARS \
    const int lane = threadIdx.x & 63, wave = threadIdx.x >> 6; \
    const int wm = wave >> 1, wn = wave & 1, lr = lane & 15, lc = lane >> 4;

// ---- Router hidden GEMM, split-K x4 (bf16 3-term, frozen) ----
__global__ __launch_bounds__(256, 2) void gemm_router(
    const ushort* __restrict__ xh, const ushort* __restrict__ xl,
    const ushort* __restrict__ wr1h, const ushort* __restrict__ wr1l,
    float* __restrict__ hpart)
{
    __shared__ ushort lds[32768];
    floatv4 acc[4][4];
    ACC_INIT(acc)

    const int kz = blockIdx.z;
    const int koff = kz * 256;
    const int brow = blockIdx.y * 128, bcol = blockIdx.x * 128;
    gemm_core_bf(xh + koff, xl + koff, wr1h + koff, wr1l + koff,
                 D_, 256, brow, bcol, lds, acc);

    float* C = hpart + (size_t)kz * ND2;
    EPI_VARS
#pragma unroll
    for (int mi = 0; mi < 4; mi++)
#pragma unroll
        for (int nj = 0; nj < 4; nj++)
#pragma unroll
            for (int i = 0; i < 4; i++) {
                int row = brow + wm * 64 + mi * 16 + lc * 4 + i;
                int col = bcol + wn * 64 + nj * 16 + lr;
                C[(size_t)row * D2_ + col] = acc[mi][nj][i];
            }
}

// ---- Fused projections (fp16): z 0..7 dense K/V, z 8..11 gathered Q ----
__global__ __launch_bounds__(256, 2) void gemm_proj(
    const _Float16* __restrict__ xfh, const _Float16* __restrict__ xfl,
    const _Float16* __restrict__ wth,
    const float* __restrict__ bq, const float* __restrict__ bk, const float* __restrict__ bv,
    const int* __restrict__ idx, const int* __restrict__ meta,
    _Float16* __restrict__ qf, _Float16* __restrict__ kf, _Float16* __restrict__ vf)
{
    __shared__ _Float16 lds[24576];
    const int z = blockIdx.z;
    const int brow = blockIdx.y * 128, bcol = blockIdx.x * 128;

    if (z < 8) {
        const int slot = z >> 1, m = z & 1;
        const size_t so = (size_t)slot * TDE;
        const _Float16* Bm = wth + (size_t)(slot * 4 + 1 + m) * WWE;   // 1=K, 2=V
        const float* bias = ((m == 0) ? bk : bv) + (size_t)slot * D_;
        _Float16* Oo = ((m == 0) ? kf : vf) + so;

        floatv4 acc[4][4];
        ACC_INIT(acc)
        gemm_core_h<false>(xfh, xfl, Bm, nullptr, D_, D_, brow, bcol, lds, acc);

        EPI_VARS
#pragma unroll
        for (int mi = 0; mi < 4; mi++)
#pragma unroll
            for (int nj = 0; nj < 4; nj++)
#pragma unroll
                for (int i = 0; i < 4; i++) {
                    int row = brow + wm * 64 + mi * 16 + lc * 4 + i;
                    int col = bcol + wn * 64 + nj * 16 + lr;
                    Oo[(size_t)row * D_ + col] = (_Float16)(acc[mi][nj][i] + bias[col]);
                }
    } else {
        const int e = z - 8;
        const int pcnt = meta[32 + e];
        if (brow >= pcnt) return;
        const int* arow = idx + e * 2048 + brow;
        const _Float16* Bm = wth + (size_t)(e * 4 + 0) * WWE;
        const float* bias = bq + (size_t)e * D_;
        const size_t so = (size_t)e * TDE;

        floatv4 acc[4][4];
        ACC_INIT(acc)
        gemm_core_h<true>(xfh, xfl, Bm, arow, D_, D_, brow, bcol, lds, acc);

        EPI_VARS
#pragma unroll
        for (int mi = 0; mi < 4; mi++)
#pragma unroll
            for (int nj = 0; nj < 4; nj++)
#pragma unroll
                for (int i = 0; i < 4; i++) {
                    int row = brow + wm * 64 + mi * 16 + lc * 4 + i;   // slot
                    int col = bcol + wn * 64 + nj * 16 + lr;
                    qf[so + (size_t)row * D_ + col] =
                        (_Float16)((acc[mi][nj][i] + bias[col]) * 0.125f);
                }
    }
}

// ---- Output projection on compacted rows + scatter into out4 slice ----
__global__ __launch_bounds__(256, 2) void gemm_combine4(
    const _Float16* __restrict__ oh, const _Float16* __restrict__ ol,
    const _Float16* __restrict__ wth,
    const float* __restrict__ bo, const float* __restrict__ emask,
    const int* __restrict__ idx, const int* __restrict__ meta,
    float* __restrict__ out4)
{
    __shared__ _Float16 lds[24576];
    const int e = blockIdx.z;
    const int pcnt = meta[32 + e];
    const int brow = blockIdx.y * 128;
    if (brow >= pcnt) return;
    const int bcol = blockIdx.x * 128;
    const size_t so = (size_t)e * TDE;
    const _Float16* Bm = wth + (size_t)(e * 4 + 3) * WWE;
    const float* bias = bo + (size_t)e * D_;
    const int* idxe = idx + e * 2048;

    floatv4 acc[4][4];
    ACC_INIT(acc)
    gemm_core_h<false>(oh + so, ol + so, Bm, nullptr, D_, D_, brow, bcol, lds, acc);

    float* dst = out4 + so;
    EPI_VARS
#pragma unroll
    for (int mi = 0; mi < 4; mi++)
#pragma unroll
        for (int nj = 0; nj < 4; nj++)
#pragma unroll
            for (int i = 0; i < 4; i++) {
                int srow = brow + wm * 64 + mi * 16 + lc * 4 + i;
                int raw = idxe[srow];
                if (raw >= 0) {   // bit31 = pad flag
                    float s = emask[(size_t)raw * E_ + e];
                    int col = bcol + wn * 64 + nj * 16 + lr;
                    dst[(size_t)raw * D_ + col] = s * (acc[mi][nj][i] + bias[col]);
                }
            }
}

// ---- reduce out4 slices -> out ----
__global__ __launch_bounds__(256) void reduce_out(
    const float* __restrict__ out4, float* __restrict__ out)
{
    size_t i = (size_t)blockIdx.x * 256 + threadIdx.x;
    const float4* p = (const float4*)out4;
    float4 a = p[i], b = p[i + TDE / 4], c = p[i + 2 * (TDE / 4)], d = p[i + 3 * (TDE / 4)];
    float4 r;
    r.x = a.x + b.x + c.x + d.x;
    r.y = a.y + b.y + c.y + d.y;
    r.z = a.z + b.z + c.z + d.z;
    r.w = a.w + b.w + c.w + d.w;
    ((float4*)out)[i] = r;
}

// ---------------------------------------------------------------------------
// Per-(expert,batch) routed-token lists, 64-padded, deterministic order.
// ---------------------------------------------------------------------------
__global__ __launch_bounds__(256) void build_lists(
    const float* __restrict__ emask, int* __restrict__ idx, int* __restrict__ meta)
{
    const int e = blockIdx.x;
    const int tid = threadIdx.x;
    __shared__ int scan[256];
    __shared__ int runsh;
    if (tid == 0) runsh = 0;
    int* idxe = idx + e * 2048;

    for (int b = 0; b < B_; b++) {
        __syncthreads();
        const int base = runsh;
        int t0 = b * 512 + tid * 2;
        int f0 = (emask[(size_t)t0 * E_ + e] != 0.f) ? 1 : 0;
        int f1 = (emask[(size_t)(t0 + 1) * E_ + e] != 0.f) ? 1 : 0;
        int my = f0 + f1;
        scan[tid] = my;
        __syncthreads();
        for (int off = 1; off < 256; off <<= 1) {
            int v = (tid >= off) ? scan[tid - off] : 0;
            __syncthreads();
            scan[tid] += v;
            __syncthreads();
        }
        int excl = scan[tid] - my;
        int cnt = scan[255];
        if (f0) idxe[base + excl] = t0;
        if (f1) idxe[base + excl + f0] = t0 + 1;
        int plen = (cnt + 63) & ~63;
        for (int i = cnt + tid; i < plen; i += 256)
            idxe[base + i] = (b * 512) | (int)0x80000000;
        if (tid == 0) {
            meta[e * 4 + b] = base;
            meta[16 + e * 4 + b] = plen >> 6;
            runsh = base + plen;
        }
    }
    __syncthreads();
    int total = runsh;
    if (tid == 0) meta[32 + e] = total;
    for (int i = total + tid; i < 2048; i += 256)
        idxe[i] = (int)0x80000000;
}

// ---------------------------------------------------------------------------
// MFMA flash attention, single-fp16 Q/K/V/P, split-fp16 O out.
// grid (8, B*H, E); per-(e,b) Q-tile count from meta. K/V dense.
// ---------------------------------------------------------------------------
__global__ __launch_bounds__(256, 2) void attn_all(
    const _Float16* __restrict__ qf_, const _Float16* __restrict__ kf_,
    const _Float16* __restrict__ vf_,
    _Float16* __restrict__ oh_, _Float16* __restrict__ ol_,
    const int* __restrict__ meta)
{
    const int e = blockIdx.z;
    const int bhid = blockIdx.y, bb = bhid >> 4, hh = bhid & 15;
    const int ptiles = meta[16 + e * 4 + bb];
    if ((int)blockIdx.x >= ptiles) return;
    const int pstart = meta[e * 4 + bb];

    __shared__ _Float16 Kf[4096];       // [64][64] f16, chunk-swizzled
    __shared__ _Float16 Vt[64 * 72];    // [d][k+pad]
    __shared__ _Float16 Pw[4][16 * 72]; // per-wave P

    const size_t zo = (size_t)e * TDE;
    const int tid = threadIdx.x;
    const int wave = tid >> 6, lane = tid & 63;
    const int lr = lane & 15, lc = lane >> 4;
    const int q0 = pstart + blockIdx.x * 64;
    const size_t kvbase = zo + (size_t)bb * S_ * D_ + hh * 64;
    const size_t qobase = zo + hh * 64;

    halfv8 qq[2];
    {
        size_t qoff = qobase + (size_t)(q0 + wave * 16 + lr) * D_ + lc * 8;
        qq[0] = *(const halfv8*)(qf_ + qoff);
        qq[1] = *(const halfv8*)(qf_ + qoff + 32);
    }

    floatv4 ov[4];
    float m4[4], l4[4];
#pragma unroll
    for (int df = 0; df < 4; df++)
#pragma unroll
        for (int i = 0; i < 4; i++) ov[df][i] = 0.f;
#pragma unroll
    for (int i = 0; i < 4; i++) { m4[i] = -3.0e38f; l4[i] = 0.f; }

    for (int kt = 0; kt < S_ / 64; kt++) {
        const int kk0 = kt * 64;
        __syncthreads();

        // stage K (swizzled source, linear LDS dest): 2 x 256 threads x 16B
#pragma unroll
        for (int s = 0; s < 2; s++) {
            int p = s * 256 + tid;
            int r = p >> 3;
            int c = (p & 7) ^ (r & 7);
            gload16(kf_ + kvbase + (size_t)(kk0 + r) * D_ + c * 8, Kf + p * 8);
        }
        // stage V transposed: wave owns d-chunk, lane = k
        {
            const _Float16* vsrc = vf_ + kvbase + (size_t)(kk0 + lane) * D_ + wave * 16;
            halfv8 v0 = *(const halfv8*)vsrc;
            halfv8 v1 = *(const halfv8*)(vsrc + 8);
#pragma unroll
            for (int j = 0; j < 8; j++) Vt[(wave * 16 + j) * 72 + lane] = v0[j];
#pragma unroll
            for (int j = 0; j < 8; j++) Vt[(wave * 16 + 8 + j) * 72 + lane] = v1[j];
        }
        __syncthreads();

        // QK^T: 16q x 64k per wave (Q pre-scaled by 1/8)
        floatv4 sc[4];
#pragma unroll
        for (int n = 0; n < 4; n++)
#pragma unroll
            for (int i = 0; i < 4; i++) sc[n][i] = 0.f;
#pragma unroll
        for (int n = 0; n < 4; n++)
#pragma unroll
            for (int ds = 0; ds < 2; ds++) {
                int off = (16 * n + lr) * 64 + (((ds * 4 + lc) ^ (lr & 7)) * 8);
                halfv8 kr = *(const halfv8*)(Kf + off);
                sc[n] = __builtin_amdgcn_mfma_f32_16x16x32_f16(qq[ds], kr, sc[n], 0, 0, 0);
            }

        float tm[4];
#pragma unroll
        for (int i = 0; i < 4; i++)
            tm[i] = fmaxf(fmaxf(sc[0][i], sc[1][i]), fmaxf(sc[2][i], sc[3][i]));
#pragma unroll
        for (int off = 1; off <= 8; off <<= 1)
#pragma unroll
            for (int i = 0; i < 4; i++)
                tm[i] = fmaxf(tm[i], __shfl_xor(tm[i], off));

        float nm[4], sca[4], ps[4];
#pragma unroll
        for (int i = 0; i < 4; i++) {
            nm[i] = fmaxf(m4[i], tm[i]);
            sca[i] = __expf(m4[i] - nm[i]);
            ps[i] = 0.f;
        }
        float pval[4][4];
#pragma unroll
        for (int n = 0; n < 4; n++)
#pragma unroll
            for (int i = 0; i < 4; i++) {
                float p = __expf(sc[n][i] - nm[i]);
                pval[n][i] = p;
                ps[i] += p;
            }
#pragma unroll
        for (int off = 1; off <= 8; off <<= 1)
#pragma unroll
            for (int i = 0; i < 4; i++)
                ps[i] += __shfl_xor(ps[i], off);
#pragma unroll
        for (int i = 0; i < 4; i++) {
            l4[i] = l4[i] * sca[i] + ps[i];
            m4[i] = nm[i];
        }
#pragma unroll
        for (int df = 0; df < 4; df++)
#pragma unroll
            for (int i = 0; i < 4; i++) ov[df][i] *= sca[i];

#pragma unroll
        for (int n = 0; n < 4; n++)
#pragma unroll
            for (int i = 0; i < 4; i++)
                Pw[wave][(lc * 4 + i) * 72 + 16 * n + lr] = (_Float16)pval[n][i];
        __syncthreads();

#pragma unroll
        for (int ks = 0; ks < 2; ks++) {
            halfv8 pa = *(const halfv8*)(&Pw[wave][lr * 72 + ks * 32 + lc * 8]);
#pragma unroll
            for (int df = 0; df < 4; df++) {
                halfv8 vr = *(const halfv8*)(Vt + (df * 16 + lr) * 72 + ks * 32 + lc * 8);
                ov[df] = __builtin_amdgcn_mfma_f32_16x16x32_f16(pa, vr, ov[df], 0, 0, 0);
            }
        }
    }

#pragma unroll
    for (int df = 0; df < 4; df++)
#pragma unroll
        for (int i = 0; i < 4; i++) {
            float val = ov[df][i] / l4[i];
            size_t off = qobase + (size_t)(q0 + wave * 16 + lc * 4 + i) * D_ + df * 16 + lr;
            _Float16 h = (_Float16)val;
            oh_[off] = h;
            ol_[off] = (_Float16)(val - (float)h);
        }
}

// ---------------------------------------------------------------------------
// Split x: bf16 hi/lo (router path) + fp16 hi/lo (main path)
// ---------------------------------------------------------------------------
__global__ __launch_bounds__(256) void split_f32(
    const float* __restrict__ in, ushort* __restrict__ hb, ushort* __restrict__ lb,
    _Float16* __restrict__ hf, _Float16* __restrict__ lf)
{
    int i = blockIdx.x * 256 + threadIdx.x;
    float4 v = ((const float4*)in)[i];
    float vv[4] = {v.x, v.y, v.z, v.w};
    ushortv4 hv, lv;
    halfv4 hhv, hlv;
#pragma unroll
    for (int j = 0; j < 4; j++) {
        ushort h = f2bf(vv[j]);
        hv[j] = h;
        lv[j] = f2bf(vv[j] - bf2f(h));
        _Float16 fh = (_Float16)vv[j];
        hhv[j] = fh;
        hlv[j] = (_Float16)(vv[j] - (float)fh);
    }
    ((ushortv4*)hb)[i] = hv;
    ((ushortv4*)lb)[i] = lv;
    ((halfv4*)hf)[i] = hhv;
    ((halfv4*)lf)[i] = hlv;
}

// ---------------------------------------------------------------------------
// Router weight transpose + bf16 split (frozen): W[K][N] -> Th/Tl[N][K]
// ---------------------------------------------------------------------------
__global__ __launch_bounds__(256) void tsplit(
    const float* __restrict__ W, ushort* __restrict__ Th, ushort* __restrict__ Tl,
    int K, int N)
{
    __shared__ float tile[64][65];
    const int n0 = blockIdx.x * 64, k0 = blockIdx.y * 64;
    const int tid = threadIdx.x;
#pragma unroll
    for (int i = 0; i < 16; i++) {
        int idx = i * 256 + tid;
        int r = idx >> 6, c = idx & 63;
        tile[r][c] = W[(size_t)(k0 + r) * N + n0 + c];
    }
    __syncthreads();
#pragma unroll
    for (int i = 0; i < 16; i++) {
        int idx = i * 256 + tid;
        int rn = idx >> 6, ck = idx & 63;
        float v = tile[ck][rn];
        ushort h = f2bf(v);
        Th[(size_t)(n0 + rn) * K + k0 + ck] = h;
        Tl[(size_t)(n0 + rn) * K + k0 + ck] = f2bf(v - bf2f(h));
    }
}

// ---- attention weights: transpose + single-fp16 round ----
__global__ __launch_bounds__(256) void tsplit16h(
    const float* __restrict__ Wq, const float* __restrict__ Wk,
    const float* __restrict__ Wv, const float* __restrict__ Wo,
    _Float16* __restrict__ Th)
{
    __shared__ float tile[64][65];
    const int mg = blockIdx.z;
    const int e = mg >> 2, m = mg & 3;
    const float* W = ((m == 0) ? Wq : (m == 1) ? Wk : (m == 2) ? Wv : Wo) + (size_t)e * WWE;
    _Float16* T = Th + (size_t)mg * WWE;
    const int n0 = blockIdx.x * 64, k0 = blockIdx.y * 64;
    const int tid = threadIdx.x;
#pragma unroll
    for (int i = 0; i < 16; i++) {
        int idx = i * 256 + tid;
        int r = idx >> 6, c = idx & 63;
        tile[r][c] = W[(size_t)(k0 + r) * D_ + n0 + c];
    }
    __syncthreads();
#pragma unroll
    for (int i = 0; i < 16; i++) {
        int idx = i * 256 + tid;
        int rn = idx >> 6, ck = idx & 63;
        T[(size_t)(n0 + rn) * D_ + k0 + ck] = (_Float16)tile[ck][rn];
    }
}

// ---------------------------------------------------------------------------
// Router post (frozen): sums 4 split-K partials + bias, LN, relu, logits,
// softmax, top2 -> emask
// ---------------------------------------------------------------------------
__global__ __launch_bounds__(256) void router_post(
    const float* __restrict__ hpart, const float* __restrict__ br1,
    const float* __restrict__ ln_g, const float* __restrict__ ln_b,
    const float* __restrict__ Wr2, const float* __restrict__ br2,
    float* __restrict__ emask)
{
    const int t = blockIdx.x;
    const int tid = threadIdx.x;
    __shared__ float red[256];
    __shared__ float logits[E_];

    const float* hp = hpart + (size_t)t * D2_;
    float x0 = hp[tid] + hp[ND2 + tid] + hp[2 * ND2 + tid] + hp[3 * ND2 + tid] + br1[tid];
    float x1 = hp[tid + 256] + hp[ND2 + tid + 256] + hp[2 * ND2 + tid + 256]
             + hp[3 * ND2 + tid + 256] + br1[tid + 256];

    red[tid] = x0 + x1; __syncthreads();
    for (int off = 128; off; off >>= 1) { if (tid < off) red[tid] += red[tid + off]; __syncthreads(); }
    float mu = red[0] * (1.f / 512.f);
    __syncthreads();

    float d0 = x0 - mu, d1 = x1 - mu;
    red[tid] = d0 * d0 + d1 * d1; __syncthreads();
    for (int off = 128; off; off >>= 1) { if (tid < off) red[tid] += red[tid + off]; __syncthreads(); }
    float rs = rsqrtf(red[0] * (1.f / 512.f) + 1e-5f);
    __syncthreads();

    float n0 = fmaxf(fmaf(d0 * rs, ln_g[tid],       ln_b[tid]),       0.f);
    float n1 = fmaxf(fmaf(d1 * rs, ln_g[tid + 256], ln_b[tid + 256]), 0.f);

    for (int e = 0; e < E_; e++) {
        red[tid] = n0 * Wr2[(size_t)tid * E_ + e] + n1 * Wr2[(size_t)(tid + 256) * E_ + e];
        __syncthreads();
        for (int off = 128; off; off >>= 1) { if (tid < off) red[tid] += red[tid + off]; __syncthreads(); }
        if (tid == 0) logits[e] = red[0] + br2[e];
        __syncthreads();
    }

    if (tid == 0) {
        float mx = fmaxf(fmaxf(logits[0], logits[1]), fmaxf(logits[2], logits[3]));
        float p[E_], sum = 0.f;
        for (int e = 0; e < E_; e++) { p[e] = expf(logits[e] - mx); sum += p[e]; }
        float inv = 1.f / sum;
        for (int e = 0; e < E_; e++) p[e] *= inv;
        int i1 = 0;
        for (int e = 1; e < E_; e++) if (p[e] > p[i1]) i1 = e;
        int i2 = -1;
        for (int e = 0; e < E_; e++) { if (e == i1) continue; if (i2 < 0 || p[e] > p[i2]) i2 = e; }
        float o[E_] = {0.f, 0.f, 0.f, 0.f};
        o[i1] = p[i1]; o[i2] = p[i2];
        for (int e = 0; e < E_; e++) emask[(size_t)t * E_ + e] = o[e];
    }
}

// ---------------------------------------------------------------------------
extern "C" void kernel_launch(void* const* d_in, const int* in_sizes, int n_in,
                              void* d_out, int out_size, void* d_ws, size_t ws_size,
                              hipStream_t stream) {
    const float* x   = (const float*)d_in[0];
    const float* Wq  = (const float*)d_in[1];
    const float* bq  = (const float*)d_in[2];
    const float* Wk  = (const float*)d_in[3];
    const float* bk  = (const float*)d_in[4];
    const float* Wv  = (const float*)d_in[5];
    const float* bv  = (const float*)d_in[6];
    const float* Wo  = (const float*)d_in[7];
    const float* bo  = (const float*)d_in[8];
    const float* Wr1 = (const float*)d_in[9];
    const float* br1 = (const float*)d_in[10];
    const float* lng = (const float*)d_in[11];
    const float* lnb = (const float*)d_in[12];
    const float* Wr2 = (const float*)d_in[13];
    const float* br2 = (const float*)d_in[14];

    float* out = (float*)d_out;
    char* w = (char*)d_ws;
    dim3 blk(256);
    const size_t MB = 1024ull * 1024ull;

    // flat layout, ~179 MB (ws >= 185 MB proven in r3-r5)
    float*    emask = (float*)w;                         // 32 KB
    int*      idx   = (int*)(w + 64 * 1024);             // 32 KB
    int*      meta  = (int*)(w + 96 * 1024);             // 144 B
    _Float16* wth   = (_Float16*)(w + 1 * MB);           // 32 MB (16 mats f16)
    ushort*   wr1h  = (ushort*)(w + 33 * MB);            // 1 MB (router bf16)
    ushort*   wr1l  = (ushort*)(w + 34 * MB);
    ushort*   xh    = (ushort*)(w + 35 * MB);            // 4 MB (router bf16)
    ushort*   xl    = (ushort*)(w + 39 * MB);
    _Float16* xfh   = (_Float16*)(w + 43 * MB);          // 4 MB (main fp16)
    _Float16* xfl   = (_Float16*)(w + 47 * MB);
    float*    hpart = (float*)(w + 51 * MB);             // 16 MB
    _Float16* qfb   = (_Float16*)(w + 67 * MB);          // 16 MB (4 experts)
    _Float16* kfb   = (_Float16*)(w + 83 * MB);
    _Float16* vfb   = (_Float16*)(w + 99 * MB);
    _Float16* ohb   = (_Float16*)(w + 115 * MB);
    _Float16* olb   = (_Float16*)(w + 131 * MB);
    float*    out4  = (float*)(w + 147 * MB);            // 32 MB -> ends 179 MB

    split_f32<<<dim3(NTOK * D_ / 1024), blk, 0, stream>>>(x, xh, xl, xfh, xfl);
    tsplit<<<dim3(D2_ / 64, D_ / 64), blk, 0, stream>>>(Wr1, wr1h, wr1l, D_, D2_);
    tsplit16h<<<dim3(16, 16, 16), blk, 0, stream>>>(Wq, Wk, Wv, Wo, wth);

    gemm_router<<<dim3(D2_ / 128, NTOK / 128, 4), blk, 0, stream>>>(
        xh, xl, wr1h, wr1l, hpart);
    router_post<<<dim3(NTOK), blk, 0, stream>>>(hpart, br1, lng, lnb, Wr2, br2, emask);
    build_lists<<<dim3(E_), blk, 0, stream>>>(emask, idx, meta);

    gemm_proj<<<dim3(D_ / 128, NTOK / 128, 12), blk, 0, stream>>>(
        xfh, xfl, wth, bq, bk, bv, idx, meta, qfb, kfb, vfb);

    attn_all<<<dim3(S_ / 64, B_ * H_, E_), blk, 0, stream>>>(
        qfb, kfb, vfb, ohb, olb, meta);

    hipMemsetAsync(out4, 0, 4 * TDE * sizeof(float), stream);
    gemm_combine4<<<dim3(D_ / 128, NTOK / 128, 4), blk, 0, stream>>>(
        ohb, olb, wth, bo, emask, idx, meta, out4);
    reduce_out<<<dim3(TDE / 1024), blk, 0, stream>>>(out4, out);
}

// Round 7
// 222.547 us; speedup vs baseline: 1.6319x; 1.2687x over previous
//
#include <hip/hip_runtime.h>
#include <hip/hip_bf16.h>
#include <math.h>

#define B_   4
#define S_   512
#define D_   1024
#define H_   16
#define E_   4
#define HD_  64
#define D2_  512
#define NTOK (B_*S_)   // 2048

#define TDE ((size_t)NTOK * D_)
#define WWE ((size_t)D_ * D_)
#define ND2 ((size_t)NTOK * D2_)

typedef unsigned short ushort;
typedef short shortv8 __attribute__((ext_vector_type(8)));
typedef ushort ushortv4 __attribute__((ext_vector_type(4)));
typedef _Float16 halfv8 __attribute__((ext_vector_type(8)));
typedef _Float16 halfv4 __attribute__((ext_vector_type(4)));
typedef float floatv4 __attribute__((ext_vector_type(4)));

__device__ __forceinline__ ushort f2bf(float f) {
    union { __hip_bfloat16 b; ushort u; } cv;
    cv.b = __float2bfloat16(f);
    return cv.u;
}
__device__ __forceinline__ float bf2f(ushort u) {
    union { ushort u; __hip_bfloat16 b; } cv;
    cv.u = u;
    return __bfloat162float(cv.b);
}
__device__ __forceinline__ void gload16(const void* g, void* l) {
    __builtin_amdgcn_global_load_lds(
        (const __attribute__((address_space(1))) unsigned int*)g,
        (__attribute__((address_space(3))) unsigned int*)l, 16, 0, 0);
}

// ---------------------------------------------------------------------------
// bf16 split 3-term GEMM core — ROUTER ONLY (frozen since r2; expert top-2
// decisions must never flip). 2-phase prefetch, counted vmcnt(8).
// ---------------------------------------------------------------------------
__device__ __forceinline__ void gemm_core_bf(
    const ushort* __restrict__ A0, const ushort* __restrict__ A1,
    const ushort* __restrict__ B0, const ushort* __restrict__ B1,
    int K, int klen, int brow, int bcol, ushort* lds, floatv4 acc[4][4])
{
    const int tid  = threadIdx.x;
    const int wave = tid >> 6, lane = tid & 63;
    const int wm = wave >> 1, wn = wave & 1;
    const int lr = lane & 15, lc = lane >> 4;

    const ushort* gsrc[4] = {A0, A1, B0, B1};
    size_t goff[4][2];
    int    loff[4][2];
#pragma unroll
    for (int t = 0; t < 4; t++) {
#pragma unroll
        for (int s = 0; s < 2; s++) {
            int p = s * 256 + tid;
            int m = p >> 2;
            int c = (p & 3) ^ ((m >> 1) & 3);
            int r = (t < 2) ? (brow + m) : (bcol + m);
            goff[t][s] = (size_t)r * K + c * 8;
            loff[t][s] = t * 4096 + p * 8;
        }
    }

    int aoff[4], boff[4];
#pragma unroll
    for (int i = 0; i < 4; i++) {
        int ra = wm * 64 + i * 16 + lr;
        aoff[i] = ra * 32 + ((lc ^ ((ra >> 1) & 3)) * 8);
        int rb2 = wn * 64 + i * 16 + lr;
        boff[i] = rb2 * 32 + ((lc ^ ((rb2 >> 1) & 3)) * 8);
    }

#define STAGEB_(buf, kk) \
    _Pragma("unroll") for (int t = 0; t < 4; t++) \
    _Pragma("unroll") for (int s = 0; s < 2; s++) \
        gload16(gsrc[t] + goff[t][s] + (kk), lds + (buf) * 16384 + loff[t][s]);

    STAGEB_(0, 0)

    int cur = 0;
    for (int k0 = 0; k0 < klen; k0 += 32, cur ^= 1) {
        if (k0 + 32 < klen) {
            STAGEB_(cur ^ 1, k0 + 32)
            asm volatile("s_waitcnt vmcnt(8)" ::: "memory");
        } else {
            asm volatile("s_waitcnt vmcnt(0)" ::: "memory");
        }
        __builtin_amdgcn_s_barrier();
        __builtin_amdgcn_sched_barrier(0);

        const ushort* L = lds + cur * 16384;
        shortv8 ah[4], al[4], bh[4], bl[4];
#pragma unroll
        for (int i = 0; i < 4; i++) {
            ah[i] = *(const shortv8*)(L +         aoff[i]);
            al[i] = *(const shortv8*)(L +  4096 + aoff[i]);
            bh[i] = *(const shortv8*)(L +  8192 + boff[i]);
            bl[i] = *(const shortv8*)(L + 12288 + boff[i]);
        }
#pragma unroll
        for (int mi = 0; mi < 4; mi++)
#pragma unroll
            for (int nj = 0; nj < 4; nj++) {
                acc[mi][nj] = __builtin_amdgcn_mfma_f32_16x16x32_bf16(ah[mi], bh[nj], acc[mi][nj], 0, 0, 0);
                acc[mi][nj] = __builtin_amdgcn_mfma_f32_16x16x32_bf16(ah[mi], bl[nj], acc[mi][nj], 0, 0, 0);
                acc[mi][nj] = __builtin_amdgcn_mfma_f32_16x16x32_bf16(al[mi], bh[nj], acc[mi][nj], 0, 0, 0);
            }

        asm volatile("s_waitcnt lgkmcnt(0)" ::: "memory");
        __builtin_amdgcn_sched_barrier(0);
        __builtin_amdgcn_s_barrier();
    }
#undef STAGEB_
}

// ---------------------------------------------------------------------------
// fp16 single-precision GEMM core (m97 2-tensor shape): C = A @ W^T.
// 128x128 tile, BK=32, 4 waves, 16 MFMA/K-step. Double-buffered 2x16KB LDS,
// 4 gloads/K-step, counted vmcnt(4). Same validated sync skeleton as r5/r6.
// GATHER=true: A rows from arow[] (bit31 = pad flag).
// ---------------------------------------------------------------------------
template<bool GATHER>
__device__ __forceinline__ void gemm_core_h1(
    const _Float16* __restrict__ A0, const _Float16* __restrict__ B0,
    const int* __restrict__ arow,
    int K, int klen, int brow, int bcol, _Float16* lds, floatv4 acc[4][4])
{
    const int tid  = threadIdx.x;
    const int wave = tid >> 6, lane = tid & 63;
    const int wm = wave >> 1, wn = wave & 1;
    const int lr = lane & 15, lc = lane >> 4;

    const _Float16* gsrc[2] = {A0, B0};
    size_t goff[2][2];
    int    loff[2][2];
#pragma unroll
    for (int t = 0; t < 2; t++) {
#pragma unroll
        for (int s = 0; s < 2; s++) {
            int p = s * 256 + tid;
            int m = p >> 2;
            int c = (p & 3) ^ ((m >> 1) & 3);
            int r;
            if (t == 0) r = GATHER ? (arow[m] & 0x7FFFFFFF) : (brow + m);
            else        r = bcol + m;
            goff[t][s] = (size_t)r * K + c * 8;
            loff[t][s] = t * 4096 + p * 8;
        }
    }

    int aoff[4], boff[4];
#pragma unroll
    for (int i = 0; i < 4; i++) {
        int ra = wm * 64 + i * 16 + lr;
        aoff[i] = ra * 32 + ((lc ^ ((ra >> 1) & 3)) * 8);
        int rb2 = wn * 64 + i * 16 + lr;
        boff[i] = rb2 * 32 + ((lc ^ ((rb2 >> 1) & 3)) * 8);
    }

#define STAGEH_(buf, kk) \
    _Pragma("unroll") for (int t = 0; t < 2; t++) \
    _Pragma("unroll") for (int s = 0; s < 2; s++) \
        gload16(gsrc[t] + goff[t][s] + (kk), lds + (buf) * 8192 + loff[t][s]);

    STAGEH_(0, 0)

    int cur = 0;
    for (int k0 = 0; k0 < klen; k0 += 32, cur ^= 1) {
        if (k0 + 32 < klen) {
            STAGEH_(cur ^ 1, k0 + 32)
            asm volatile("s_waitcnt vmcnt(4)" ::: "memory");
        } else {
            asm volatile("s_waitcnt vmcnt(0)" ::: "memory");
        }
        __builtin_amdgcn_s_barrier();
        __builtin_amdgcn_sched_barrier(0);

        const _Float16* L = lds + cur * 8192;
        halfv8 aa[4], bb[4];
#pragma unroll
        for (int i = 0; i < 4; i++) {
            aa[i] = *(const halfv8*)(L +        aoff[i]);
            bb[i] = *(const halfv8*)(L + 4096 + boff[i]);
        }
#pragma unroll
        for (int mi = 0; mi < 4; mi++)
#pragma unroll
            for (int nj = 0; nj < 4; nj++)
                acc[mi][nj] = __builtin_amdgcn_mfma_f32_16x16x32_f16(aa[mi], bb[nj], acc[mi][nj], 0, 0, 0);

        asm volatile("s_waitcnt lgkmcnt(0)" ::: "memory");
        __builtin_amdgcn_sched_barrier(0);
        __builtin_amdgcn_s_barrier();
    }
#undef STAGEH_
}

#define ACC_INIT(acc) \
    _Pragma("unroll") for (int i = 0; i < 4; i++) \
    _Pragma("unroll") for (int j = 0; j < 4; j++) \
    _Pragma("unroll") for (int q = 0; q < 4; q++) acc[i][j][q] = 0.f;

#define EPI_VARS \
    const int lane = threadIdx.x & 63, wave = threadIdx.x >> 6; \
    const int wm = wave >> 1, wn = wave & 1, lr = lane & 15, lc = lane >> 4;

// ---- Router hidden GEMM, split-K x4 (bf16 3-term, frozen numerics) ----
// grid (4,16,4) = 256 blocks; XCD swizzle cpx=32
__global__ __launch_bounds__(256, 2) void gemm_router(
    const ushort* __restrict__ xh, const ushort* __restrict__ xl,
    const ushort* __restrict__ wr1h, const ushort* __restrict__ wr1l,
    float* __restrict__ hpart)
{
    __shared__ ushort lds[32768];
    floatv4 acc[4][4];
    ACC_INIT(acc)

    const int lid = blockIdx.x + 4 * (blockIdx.y + 16 * blockIdx.z);
    const int nid = (lid & 7) * 32 + (lid >> 3);
    const int kz = nid >> 6;
    const int rem = nid & 63;
    const int brow = (rem >> 2) * 128, bcol = (rem & 3) * 128;

    const int koff = kz * 256;
    gemm_core_bf(xh + koff, xl + koff, wr1h + koff, wr1l + koff,
                 D_, 256, brow, bcol, lds, acc);

    float* C = hpart + (size_t)kz * ND2;
    EPI_VARS
#pragma unroll
    for (int mi = 0; mi < 4; mi++)
#pragma unroll
        for (int nj = 0; nj < 4; nj++)
#pragma unroll
            for (int i = 0; i < 4; i++) {
                int row = brow + wm * 64 + mi * 16 + lc * 4 + i;
                int col = bcol + wn * 64 + nj * 16 + lr;
                C[(size_t)row * D2_ + col] = acc[mi][nj][i];
            }
}

// ---- Fused projections (single fp16): z 0..7 dense K/V, z 8..11 gathered Q
// grid (8,16,12) = 1536 blocks; XCD swizzle cpx=192
__global__ __launch_bounds__(256, 2) void gemm_proj(
    const _Float16* __restrict__ xf,
    const _Float16* __restrict__ wth,
    const float* __restrict__ bq, const float* __restrict__ bk, const float* __restrict__ bv,
    const int* __restrict__ idx, const int* __restrict__ meta,
    _Float16* __restrict__ qf, _Float16* __restrict__ kf, _Float16* __restrict__ vf)
{
    __shared__ _Float16 lds[16384];
    const int lid = blockIdx.x + 8 * (blockIdx.y + 16 * blockIdx.z);
    const int nid = (lid & 7) * 192 + (lid >> 3);
    const int z = nid >> 7;
    const int rem = nid & 127;
    const int brow = (rem >> 3) * 128, bcol = (rem & 7) * 128;

    if (z < 8) {
        const int slot = z >> 1, m = z & 1;
        const size_t so = (size_t)slot * TDE;
        const _Float16* Bm = wth + (size_t)(slot * 4 + 1 + m) * WWE;   // 1=K, 2=V
        const float* bias = ((m == 0) ? bk : bv) + (size_t)slot * D_;
        _Float16* Oo = ((m == 0) ? kf : vf) + so;

        floatv4 acc[4][4];
        ACC_INIT(acc)
        gemm_core_h1<false>(xf, Bm, nullptr, D_, D_, brow, bcol, lds, acc);

        EPI_VARS
#pragma unroll
        for (int mi = 0; mi < 4; mi++)
#pragma unroll
            for (int nj = 0; nj < 4; nj++)
#pragma unroll
                for (int i = 0; i < 4; i++) {
                    int row = brow + wm * 64 + mi * 16 + lc * 4 + i;
                    int col = bcol + wn * 64 + nj * 16 + lr;
                    Oo[(size_t)row * D_ + col] = (_Float16)(acc[mi][nj][i] + bias[col]);
                }
    } else {
        const int e = z - 8;
        const int pcnt = meta[32 + e];
        if (brow >= pcnt) return;
        const int* arow = idx + e * 2048 + brow;
        const _Float16* Bm = wth + (size_t)(e * 4 + 0) * WWE;
        const float* bias = bq + (size_t)e * D_;
        const size_t so = (size_t)e * TDE;

        floatv4 acc[4][4];
        ACC_INIT(acc)
        gemm_core_h1<true>(xf, Bm, arow, D_, D_, brow, bcol, lds, acc);

        EPI_VARS
#pragma unroll
        for (int mi = 0; mi < 4; mi++)
#pragma unroll
            for (int nj = 0; nj < 4; nj++)
#pragma unroll
                for (int i = 0; i < 4; i++) {
                    int row = brow + wm * 64 + mi * 16 + lc * 4 + i;   // slot
                    int col = bcol + wn * 64 + nj * 16 + lr;
                    qf[so + (size_t)row * D_ + col] =
                        (_Float16)((acc[mi][nj][i] + bias[col]) * 0.125f);
                }
    }
}

// ---- Output projection on compacted rows + scatter into out4 slice ----
// grid (8,16,4) = 512 blocks; XCD swizzle cpx=64
__global__ __launch_bounds__(256, 2) void gemm_combine4(
    const _Float16* __restrict__ oh,
    const _Float16* __restrict__ wth,
    const float* __restrict__ bo, const float* __restrict__ emask,
    const int* __restrict__ idx, const int* __restrict__ meta,
    float* __restrict__ out4)
{
    __shared__ _Float16 lds[16384];
    const int lid = blockIdx.x + 8 * (blockIdx.y + 16 * blockIdx.z);
    const int nid = (lid & 7) * 64 + (lid >> 3);
    const int e = nid >> 7;
    const int rem = nid & 127;
    const int brow = (rem >> 3) * 128, bcol = (rem & 7) * 128;

    const int pcnt = meta[32 + e];
    if (brow >= pcnt) return;
    const size_t so = (size_t)e * TDE;
    const _Float16* Bm = wth + (size_t)(e * 4 + 3) * WWE;
    const float* bias = bo + (size_t)e * D_;
    const int* idxe = idx + e * 2048;

    floatv4 acc[4][4];
    ACC_INIT(acc)
    gemm_core_h1<false>(oh + so, Bm, nullptr, D_, D_, brow, bcol, lds, acc);

    float* dst = out4 + so;
    EPI_VARS
#pragma unroll
    for (int mi = 0; mi < 4; mi++)
#pragma unroll
        for (int nj = 0; nj < 4; nj++)
#pragma unroll
            for (int i = 0; i < 4; i++) {
                int srow = brow + wm * 64 + mi * 16 + lc * 4 + i;
                int raw = idxe[srow];
                if (raw >= 0) {   // bit31 = pad flag
                    float s = emask[(size_t)raw * E_ + e];
                    int col = bcol + wn * 64 + nj * 16 + lr;
                    dst[(size_t)raw * D_ + col] = s * (acc[mi][nj][i] + bias[col]);
                }
            }
}

// ---- reduce out4 slices -> out ----
__global__ __launch_bounds__(256) void reduce_out(
    const float* __restrict__ out4, float* __restrict__ out)
{
    size_t i = (size_t)blockIdx.x * 256 + threadIdx.x;
    const float4* p = (const float4*)out4;
    float4 a = p[i], b = p[i + TDE / 4], c = p[i + 2 * (TDE / 4)], d = p[i + 3 * (TDE / 4)];
    float4 r;
    r.x = a.x + b.x + c.x + d.x;
    r.y = a.y + b.y + c.y + d.y;
    r.z = a.z + b.z + c.z + d.z;
    r.w = a.w + b.w + c.w + d.w;
    ((float4*)out)[i] = r;
}

// ---------------------------------------------------------------------------
// Per-(expert,batch) routed-token lists, 64-padded, deterministic order.
// ---------------------------------------------------------------------------
__global__ __launch_bounds__(256) void build_lists(
    const float* __restrict__ emask, int* __restrict__ idx, int* __restrict__ meta)
{
    const int e = blockIdx.x;
    const int tid = threadIdx.x;
    __shared__ int scan[256];
    __shared__ int runsh;
    if (tid == 0) runsh = 0;
    int* idxe = idx + e * 2048;

    for (int b = 0; b < B_; b++) {
        __syncthreads();
        const int base = runsh;
        int t0 = b * 512 + tid * 2;
        int f0 = (emask[(size_t)t0 * E_ + e] != 0.f) ? 1 : 0;
        int f1 = (emask[(size_t)(t0 + 1) * E_ + e] != 0.f) ? 1 : 0;
        int my = f0 + f1;
        scan[tid] = my;
        __syncthreads();
        for (int off = 1; off < 256; off <<= 1) {
            int v = (tid >= off) ? scan[tid - off] : 0;
            __syncthreads();
            scan[tid] += v;
            __syncthreads();
        }
        int excl = scan[tid] - my;
        int cnt = scan[255];
        if (f0) idxe[base + excl] = t0;
        if (f1) idxe[base + excl + f0] = t0 + 1;
        int plen = (cnt + 63) & ~63;
        for (int i = cnt + tid; i < plen; i += 256)
            idxe[base + i] = (b * 512) | (int)0x80000000;
        if (tid == 0) {
            meta[e * 4 + b] = base;
            meta[16 + e * 4 + b] = plen >> 6;
            runsh = base + plen;
        }
    }
    __syncthreads();
    int total = runsh;
    if (tid == 0) meta[32 + e] = total;
    for (int i = total + tid; i < 2048; i += 256)
        idxe[i] = (int)0x80000000;
}

// ---------------------------------------------------------------------------
// MFMA flash attention, single-fp16 Q/K/V/P/O. grid (8,64,4), XCD swizzle
// cpx=256. Per-(e,b) Q-tile count from meta; K/V dense.
// ---------------------------------------------------------------------------
__global__ __launch_bounds__(256, 2) void attn_all(
    const _Float16* __restrict__ qf_, const _Float16* __restrict__ kf_,
    const _Float16* __restrict__ vf_,
    _Float16* __restrict__ oh_,
    const int* __restrict__ meta)
{
    const int lid = blockIdx.x + 8 * (blockIdx.y + 64 * blockIdx.z);
    const int nid = (lid & 7) * 256 + (lid >> 3);
    const int e = nid >> 9;
    const int rem = nid & 511;
    const int bhid = rem >> 3, qtile = rem & 7;
    const int bb = bhid >> 4, hh = bhid & 15;

    const int ptiles = meta[16 + e * 4 + bb];
    if (qtile >= ptiles) return;
    const int pstart = meta[e * 4 + bb];

    __shared__ _Float16 Kf[4096];       // [64][64] f16, chunk-swizzled
    __shared__ _Float16 Vt[64 * 72];    // [d][k+pad]
    __shared__ _Float16 Pw[4][16 * 72]; // per-wave P

    const size_t zo = (size_t)e * TDE;
    const int tid = threadIdx.x;
    const int wave = tid >> 6, lane = tid & 63;
    const int lr = lane & 15, lc = lane >> 4;
    const int q0 = pstart + qtile * 64;
    const size_t kvbase = zo + (size_t)bb * S_ * D_ + hh * 64;
    const size_t qobase = zo + hh * 64;

    halfv8 qq[2];
    {
        size_t qoff = qobase + (size_t)(q0 + wave * 16 + lr) * D_ + lc * 8;
        qq[0] = *(const halfv8*)(qf_ + qoff);
        qq[1] = *(const halfv8*)(qf_ + qoff + 32);
    }

    floatv4 ov[4];
    float m4[4], l4[4];
#pragma unroll
    for (int df = 0; df < 4; df++)
#pragma unroll
        for (int i = 0; i < 4; i++) ov[df][i] = 0.f;
#pragma unroll
    for (int i = 0; i < 4; i++) { m4[i] = -3.0e38f; l4[i] = 0.f; }

    for (int kt = 0; kt < S_ / 64; kt++) {
        const int kk0 = kt * 64;
        __syncthreads();

#pragma unroll
        for (int s = 0; s < 2; s++) {
            int p = s * 256 + tid;
            int r = p >> 3;
            int c = (p & 7) ^ (r & 7);
            gload16(kf_ + kvbase + (size_t)(kk0 + r) * D_ + c * 8, Kf + p * 8);
        }
        {
            const _Float16* vsrc = vf_ + kvbase + (size_t)(kk0 + lane) * D_ + wave * 16;
            halfv8 v0 = *(const halfv8*)vsrc;
            halfv8 v1 = *(const halfv8*)(vsrc + 8);
#pragma unroll
            for (int j = 0; j < 8; j++) Vt[(wave * 16 + j) * 72 + lane] = v0[j];
#pragma unroll
            for (int j = 0; j < 8; j++) Vt[(wave * 16 + 8 + j) * 72 + lane] = v1[j];
        }
        __syncthreads();

        floatv4 sc[4];
#pragma unroll
        for (int n = 0; n < 4; n++)
#pragma unroll
            for (int i = 0; i < 4; i++) sc[n][i] = 0.f;
#pragma unroll
        for (int n = 0; n < 4; n++)
#pragma unroll
            for (int ds = 0; ds < 2; ds++) {
                int off = (16 * n + lr) * 64 + (((ds * 4 + lc) ^ (lr & 7)) * 8);
                halfv8 kr = *(const halfv8*)(Kf + off);
                sc[n] = __builtin_amdgcn_mfma_f32_16x16x32_f16(qq[ds], kr, sc[n], 0, 0, 0);
            }

        float tm[4];
#pragma unroll
        for (int i = 0; i < 4; i++)
            tm[i] = fmaxf(fmaxf(sc[0][i], sc[1][i]), fmaxf(sc[2][i], sc[3][i]));
#pragma unroll
        for (int off = 1; off <= 8; off <<= 1)
#pragma unroll
            for (int i = 0; i < 4; i++)
                tm[i] = fmaxf(tm[i], __shfl_xor(tm[i], off));

        float nm[4], sca[4], ps[4];
#pragma unroll
        for (int i = 0; i < 4; i++) {
            nm[i] = fmaxf(m4[i], tm[i]);
            sca[i] = __expf(m4[i] - nm[i]);
            ps[i] = 0.f;
        }
        float pval[4][4];
#pragma unroll
        for (int n = 0; n < 4; n++)
#pragma unroll
            for (int i = 0; i < 4; i++) {
                float p = __expf(sc[n][i] - nm[i]);
                pval[n][i] = p;
                ps[i] += p;
            }
#pragma unroll
        for (int off = 1; off <= 8; off <<= 1)
#pragma unroll
            for (int i = 0; i < 4; i++)
                ps[i] += __shfl_xor(ps[i], off);
#pragma unroll
        for (int i = 0; i < 4; i++) {
            l4[i] = l4[i] * sca[i] + ps[i];
            m4[i] = nm[i];
        }
#pragma unroll
        for (int df = 0; df < 4; df++)
#pragma unroll
            for (int i = 0; i < 4; i++) ov[df][i] *= sca[i];

#pragma unroll
        for (int n = 0; n < 4; n++)
#pragma unroll
            for (int i = 0; i < 4; i++)
                Pw[wave][(lc * 4 + i) * 72 + 16 * n + lr] = (_Float16)pval[n][i];
        __syncthreads();

#pragma unroll
        for (int ks = 0; ks < 2; ks++) {
            halfv8 pa = *(const halfv8*)(&Pw[wave][lr * 72 + ks * 32 + lc * 8]);
#pragma unroll
            for (int df = 0; df < 4; df++) {
                halfv8 vr = *(const halfv8*)(Vt + (df * 16 + lr) * 72 + ks * 32 + lc * 8);
                ov[df] = __builtin_amdgcn_mfma_f32_16x16x32_f16(pa, vr, ov[df], 0, 0, 0);
            }
        }
    }

#pragma unroll
    for (int df = 0; df < 4; df++)
#pragma unroll
        for (int i = 0; i < 4; i++) {
            float val = ov[df][i] / l4[i];
            size_t off = qobase + (size_t)(q0 + wave * 16 + lc * 4 + i) * D_ + df * 16 + lr;
            oh_[off] = (_Float16)val;
        }
}

// ---------------------------------------------------------------------------
// Split x: bf16 hi/lo (router path) + single fp16 (main path)
// ---------------------------------------------------------------------------
__global__ __launch_bounds__(256) void split_f32(
    const float* __restrict__ in, ushort* __restrict__ hb, ushort* __restrict__ lb,
    _Float16* __restrict__ hf)
{
    int i = blockIdx.x * 256 + threadIdx.x;
    float4 v = ((const float4*)in)[i];
    float vv[4] = {v.x, v.y, v.z, v.w};
    ushortv4 hv, lv;
    halfv4 hhv;
#pragma unroll
    for (int j = 0; j < 4; j++) {
        ushort h = f2bf(vv[j]);
        hv[j] = h;
        lv[j] = f2bf(vv[j] - bf2f(h));
        hhv[j] = (_Float16)vv[j];
    }
    ((ushortv4*)hb)[i] = hv;
    ((ushortv4*)lb)[i] = lv;
    ((halfv4*)hf)[i] = hhv;
}

// ---------------------------------------------------------------------------
// Router weight transpose + bf16 split (frozen)
// ---------------------------------------------------------------------------
__global__ __launch_bounds__(256) void tsplit(
    const float* __restrict__ W, ushort* __restrict__ Th, ushort* __restrict__ Tl,
    int K, int N)
{
    __shared__ float tile[64][65];
    const int n0 = blockIdx.x * 64, k0 = blockIdx.y * 64;
    const int tid = threadIdx.x;
#pragma unroll
    for (int i = 0; i < 16; i++) {
        int idx = i * 256 + tid;
        int r = idx >> 6, c = idx & 63;
        tile[r][c] = W[(size_t)(k0 + r) * N + n0 + c];
    }
    __syncthreads();
#pragma unroll
    for (int i = 0; i < 16; i++) {
        int idx = i * 256 + tid;
        int rn = idx >> 6, ck = idx & 63;
        float v = tile[ck][rn];
        ushort h = f2bf(v);
        Th[(size_t)(n0 + rn) * K + k0 + ck] = h;
        Tl[(size_t)(n0 + rn) * K + k0 + ck] = f2bf(v - bf2f(h));
    }
}

// ---- attention weights: transpose + single-fp16 round ----
__global__ __launch_bounds__(256) void tsplit16h(
    const float* __restrict__ Wq, const float* __restrict__ Wk,
    const float* __restrict__ Wv, const float* __restrict__ Wo,
    _Float16* __restrict__ Th)
{
    __shared__ float tile[64][65];
    const int mg = blockIdx.z;
    const int e = mg >> 2, m = mg & 3;
    const float* W = ((m == 0) ? Wq : (m == 1) ? Wk : (m == 2) ? Wv : Wo) + (size_t)e * WWE;
    _Float16* T = Th + (size_t)mg * WWE;
    const int n0 = blockIdx.x * 64, k0 = blockIdx.y * 64;
    const int tid = threadIdx.x;
#pragma unroll
    for (int i = 0; i < 16; i++) {
        int idx = i * 256 + tid;
        int r = idx >> 6, c = idx & 63;
        tile[r][c] = W[(size_t)(k0 + r) * D_ + n0 + c];
    }
    __syncthreads();
#pragma unroll
    for (int i = 0; i < 16; i++) {
        int idx = i * 256 + tid;
        int rn = idx >> 6, ck = idx & 63;
        T[(size_t)(n0 + rn) * D_ + k0 + ck] = (_Float16)tile[ck][rn];
    }
}

// ---------------------------------------------------------------------------
// Router post (frozen)
// ---------------------------------------------------------------------------
__global__ __launch_bounds__(256) void router_post(
    const float* __restrict__ hpart, const float* __restrict__ br1,
    const float* __restrict__ ln_g, const float* __restrict__ ln_b,
    const float* __restrict__ Wr2, const float* __restrict__ br2,
    float* __restrict__ emask)
{
    const int t = blockIdx.x;
    const int tid = threadIdx.x;
    __shared__ float red[256];
    __shared__ float logits[E_];

    const float* hp = hpart + (size_t)t * D2_;
    float x0 = hp[tid] + hp[ND2 + tid] + hp[2 * ND2 + tid] + hp[3 * ND2 + tid] + br1[tid];
    float x1 = hp[tid + 256] + hp[ND2 + tid + 256] + hp[2 * ND2 + tid + 256]
             + hp[3 * ND2 + tid + 256] + br1[tid + 256];

    red[tid] = x0 + x1; __syncthreads();
    for (int off = 128; off; off >>= 1) { if (tid < off) red[tid] += red[tid + off]; __syncthreads(); }
    float mu = red[0] * (1.f / 512.f);
    __syncthreads();

    float d0 = x0 - mu, d1 = x1 - mu;
    red[tid] = d0 * d0 + d1 * d1; __syncthreads();
    for (int off = 128; off; off >>= 1) { if (tid < off) red[tid] += red[tid + off]; __syncthreads(); }
    float rs = rsqrtf(red[0] * (1.f / 512.f) + 1e-5f);
    __syncthreads();

    float n0 = fmaxf(fmaf(d0 * rs, ln_g[tid],       ln_b[tid]),       0.f);
    float n1 = fmaxf(fmaf(d1 * rs, ln_g[tid + 256], ln_b[tid + 256]), 0.f);

    for (int e = 0; e < E_; e++) {
        red[tid] = n0 * Wr2[(size_t)tid * E_ + e] + n1 * Wr2[(size_t)(tid + 256) * E_ + e];
        __syncthreads();
        for (int off = 128; off; off >>= 1) { if (tid < off) red[tid] += red[tid + off]; __syncthreads(); }
        if (tid == 0) logits[e] = red[0] + br2[e];
        __syncthreads();
    }

    if (tid == 0) {
        float mx = fmaxf(fmaxf(logits[0], logits[1]), fmaxf(logits[2], logits[3]));
        float p[E_], sum = 0.f;
        for (int e = 0; e < E_; e++) { p[e] = expf(logits[e] - mx); sum += p[e]; }
        float inv = 1.f / sum;
        for (int e = 0; e < E_; e++) p[e] *= inv;
        int i1 = 0;
        for (int e = 1; e < E_; e++) if (p[e] > p[i1]) i1 = e;
        int i2 = -1;
        for (int e = 0; e < E_; e++) { if (e == i1) continue; if (i2 < 0 || p[e] > p[i2]) i2 = e; }
        float o[E_] = {0.f, 0.f, 0.f, 0.f};
        o[i1] = p[i1]; o[i2] = p[i2];
        for (int e = 0; e < E_; e++) emask[(size_t)t * E_ + e] = o[e];
    }
}

// ---------------------------------------------------------------------------
extern "C" void kernel_launch(void* const* d_in, const int* in_sizes, int n_in,
                              void* d_out, int out_size, void* d_ws, size_t ws_size,
                              hipStream_t stream) {
    const float* x   = (const float*)d_in[0];
    const float* Wq  = (const float*)d_in[1];
    const float* bq  = (const float*)d_in[2];
    const float* Wk  = (const float*)d_in[3];
    const float* bk  = (const float*)d_in[4];
    const float* Wv  = (const float*)d_in[5];
    const float* bv  = (const float*)d_in[6];
    const float* Wo  = (const float*)d_in[7];
    const float* bo  = (const float*)d_in[8];
    const float* Wr1 = (const float*)d_in[9];
    const float* br1 = (const float*)d_in[10];
    const float* lng = (const float*)d_in[11];
    const float* lnb = (const float*)d_in[12];
    const float* Wr2 = (const float*)d_in[13];
    const float* br2 = (const float*)d_in[14];

    float* out = (float*)d_out;
    char* w = (char*)d_ws;
    dim3 blk(256);
    const size_t MB = 1024ull * 1024ull;

    // flat layout, ~159 MB (ws >= 185 MB proven r3-r6)
    float*    emask = (float*)w;                         // 32 KB
    int*      idx   = (int*)(w + 64 * 1024);             // 32 KB
    int*      meta  = (int*)(w + 96 * 1024);             // 144 B
    _Float16* wth   = (_Float16*)(w + 1 * MB);           // 32 MB (16 mats f16)
    ushort*   wr1h  = (ushort*)(w + 33 * MB);            // 1 MB (router bf16)
    ushort*   wr1l  = (ushort*)(w + 34 * MB);
    ushort*   xh    = (ushort*)(w + 35 * MB);            // 4 MB (router bf16)
    ushort*   xl    = (ushort*)(w + 39 * MB);
    _Float16* xfh   = (_Float16*)(w + 43 * MB);          // 4 MB (main fp16)
    float*    hpart = (float*)(w + 47 * MB);             // 16 MB
    _Float16* qfb   = (_Float16*)(w + 63 * MB);          // 16 MB (4 experts)
    _Float16* kfb   = (_Float16*)(w + 79 * MB);
    _Float16* vfb   = (_Float16*)(w + 95 * MB);
    _Float16* ohb   = (_Float16*)(w + 111 * MB);
    float*    out4  = (float*)(w + 127 * MB);            // 32 MB -> ends 159 MB

    split_f32<<<dim3(NTOK * D_ / 1024), blk, 0, stream>>>(x, xh, xl, xfh);
    tsplit<<<dim3(D2_ / 64, D_ / 64), blk, 0, stream>>>(Wr1, wr1h, wr1l, D_, D2_);
    tsplit16h<<<dim3(16, 16, 16), blk, 0, stream>>>(Wq, Wk, Wv, Wo, wth);

    gemm_router<<<dim3(D2_ / 128, NTOK / 128, 4), blk, 0, stream>>>(
        xh, xl, wr1h, wr1l, hpart);
    router_post<<<dim3(NTOK), blk, 0, stream>>>(hpart, br1, lng, lnb, Wr2, br2, emask);
    build_lists<<<dim3(E_), blk, 0, stream>>>(emask, idx, meta);

    gemm_proj<<<dim3(D_ / 128, NTOK / 128, 12), blk, 0, stream>>>(
        xfh, wth, bq, bk, bv, idx, meta, qfb, kfb, vfb);

    attn_all<<<dim3(S_ / 64, B_ * H_, E_), blk, 0, stream>>>(
        qfb, kfb, vfb, ohb, meta);

    hipMemsetAsync(out4, 0, 4 * TDE * sizeof(float), stream);
    gemm_combine4<<<dim3(D_ / 128, NTOK / 128, 4), blk, 0, stream>>>(
        ohb, wth, bo, emask, idx, meta, out4);
    reduce_out<<<dim3(TDE / 1024), blk, 0, stream>>>(out4, out);
}

// Round 8
// 215.377 us; speedup vs baseline: 1.6862x; 1.0333x over previous
//
#include <hip/hip_runtime.h>
#include <hip/hip_bf16.h>
#include <math.h>

#define B_   4
#define S_   512
#define D_   1024
#define H_   16
#define E_   4
#define HD_  64
#define D2_  512
#define NTOK (B_*S_)   // 2048

#define TDE ((size_t)NTOK * D_)
#define WWE ((size_t)D_ * D_)
#define ND2 ((size_t)NTOK * D2_)

typedef unsigned short ushort;
typedef short shortv8 __attribute__((ext_vector_type(8)));
typedef ushort ushortv4 __attribute__((ext_vector_type(4)));
typedef _Float16 halfv8 __attribute__((ext_vector_type(8)));
typedef _Float16 halfv4 __attribute__((ext_vector_type(4)));
typedef float floatv4 __attribute__((ext_vector_type(4)));

__device__ __forceinline__ ushort f2bf(float f) {
    union { __hip_bfloat16 b; ushort u; } cv;
    cv.b = __float2bfloat16(f);
    return cv.u;
}
__device__ __forceinline__ float bf2f(ushort u) {
    union { ushort u; __hip_bfloat16 b; } cv;
    cv.u = u;
    return __bfloat162float(cv.b);
}
__device__ __forceinline__ void gload16(const void* g, void* l) {
    __builtin_amdgcn_global_load_lds(
        (const __attribute__((address_space(1))) unsigned int*)g,
        (__attribute__((address_space(3))) unsigned int*)l, 16, 0, 0);
}

// ---------------------------------------------------------------------------
// bf16 split 3-term GEMM core — ROUTER ONLY (frozen since r2).
// ---------------------------------------------------------------------------
__device__ __forceinline__ void gemm_core_bf(
    const ushort* __restrict__ A0, const ushort* __restrict__ A1,
    const ushort* __restrict__ B0, const ushort* __restrict__ B1,
    int K, int klen, int brow, int bcol, ushort* lds, floatv4 acc[4][4])
{
    const int tid  = threadIdx.x;
    const int wave = tid >> 6, lane = tid & 63;
    const int wm = wave >> 1, wn = wave & 1;
    const int lr = lane & 15, lc = lane >> 4;

    const ushort* gsrc[4] = {A0, A1, B0, B1};
    size_t goff[4][2];
    int    loff[4][2];
#pragma unroll
    for (int t = 0; t < 4; t++) {
#pragma unroll
        for (int s = 0; s < 2; s++) {
            int p = s * 256 + tid;
            int m = p >> 2;
            int c = (p & 3) ^ ((m >> 1) & 3);
            int r = (t < 2) ? (brow + m) : (bcol + m);
            goff[t][s] = (size_t)r * K + c * 8;
            loff[t][s] = t * 4096 + p * 8;
        }
    }

    int aoff[4], boff[4];
#pragma unroll
    for (int i = 0; i < 4; i++) {
        int ra = wm * 64 + i * 16 + lr;
        aoff[i] = ra * 32 + ((lc ^ ((ra >> 1) & 3)) * 8);
        int rb2 = wn * 64 + i * 16 + lr;
        boff[i] = rb2 * 32 + ((lc ^ ((rb2 >> 1) & 3)) * 8);
    }

#define STAGEB_(buf, kk) \
    _Pragma("unroll") for (int t = 0; t < 4; t++) \
    _Pragma("unroll") for (int s = 0; s < 2; s++) \
        gload16(gsrc[t] + goff[t][s] + (kk), lds + (buf) * 16384 + loff[t][s]);

    STAGEB_(0, 0)

    int cur = 0;
    for (int k0 = 0; k0 < klen; k0 += 32, cur ^= 1) {
        if (k0 + 32 < klen) {
            STAGEB_(cur ^ 1, k0 + 32)
            asm volatile("s_waitcnt vmcnt(8)" ::: "memory");
        } else {
            asm volatile("s_waitcnt vmcnt(0)" ::: "memory");
        }
        __builtin_amdgcn_s_barrier();
        __builtin_amdgcn_sched_barrier(0);

        const ushort* L = lds + cur * 16384;
        shortv8 ah[4], al[4], bh[4], bl[4];
#pragma unroll
        for (int i = 0; i < 4; i++) {
            ah[i] = *(const shortv8*)(L +         aoff[i]);
            al[i] = *(const shortv8*)(L +  4096 + aoff[i]);
            bh[i] = *(const shortv8*)(L +  8192 + boff[i]);
            bl[i] = *(const shortv8*)(L + 12288 + boff[i]);
        }
#pragma unroll
        for (int mi = 0; mi < 4; mi++)
#pragma unroll
            for (int nj = 0; nj < 4; nj++) {
                acc[mi][nj] = __builtin_amdgcn_mfma_f32_16x16x32_bf16(ah[mi], bh[nj], acc[mi][nj], 0, 0, 0);
                acc[mi][nj] = __builtin_amdgcn_mfma_f32_16x16x32_bf16(ah[mi], bl[nj], acc[mi][nj], 0, 0, 0);
                acc[mi][nj] = __builtin_amdgcn_mfma_f32_16x16x32_bf16(al[mi], bh[nj], acc[mi][nj], 0, 0, 0);
            }

        asm volatile("s_waitcnt lgkmcnt(0)" ::: "memory");
        __builtin_amdgcn_sched_barrier(0);
        __builtin_amdgcn_s_barrier();
    }
#undef STAGEB_
}

// ---------------------------------------------------------------------------
// fp16 single GEMM core (m97 2-tensor shape), validated r7 sync skeleton.
// GATHER=true: A rows from arow[] (low 16 bits = row; bit31 = pad).
// ---------------------------------------------------------------------------
template<bool GATHER>
__device__ __forceinline__ void gemm_core_h1(
    const _Float16* __restrict__ A0, const _Float16* __restrict__ B0,
    const int* __restrict__ arow,
    int K, int klen, int brow, int bcol, _Float16* lds, floatv4 acc[4][4])
{
    const int tid  = threadIdx.x;
    const int wave = tid >> 6, lane = tid & 63;
    const int wm = wave >> 1, wn = wave & 1;
    const int lr = lane & 15, lc = lane >> 4;

    const _Float16* gsrc[2] = {A0, B0};
    size_t goff[2][2];
    int    loff[2][2];
#pragma unroll
    for (int t = 0; t < 2; t++) {
#pragma unroll
        for (int s = 0; s < 2; s++) {
            int p = s * 256 + tid;
            int m = p >> 2;
            int c = (p & 3) ^ ((m >> 1) & 3);
            int r;
            if (t == 0) r = GATHER ? (arow[m] & 0xFFFF) : (brow + m);
            else        r = bcol + m;
            goff[t][s] = (size_t)r * K + c * 8;
            loff[t][s] = t * 4096 + p * 8;
        }
    }

    int aoff[4], boff[4];
#pragma unroll
    for (int i = 0; i < 4; i++) {
        int ra = wm * 64 + i * 16 + lr;
        aoff[i] = ra * 32 + ((lc ^ ((ra >> 1) & 3)) * 8);
        int rb2 = wn * 64 + i * 16 + lr;
        boff[i] = rb2 * 32 + ((lc ^ ((rb2 >> 1) & 3)) * 8);
    }

#define STAGEH_(buf, kk) \
    _Pragma("unroll") for (int t = 0; t < 2; t++) \
    _Pragma("unroll") for (int s = 0; s < 2; s++) \
        gload16(gsrc[t] + goff[t][s] + (kk), lds + (buf) * 8192 + loff[t][s]);

    STAGEH_(0, 0)

    int cur = 0;
    for (int k0 = 0; k0 < klen; k0 += 32, cur ^= 1) {
        if (k0 + 32 < klen) {
            STAGEH_(cur ^ 1, k0 + 32)
            asm volatile("s_waitcnt vmcnt(4)" ::: "memory");
        } else {
            asm volatile("s_waitcnt vmcnt(0)" ::: "memory");
        }
        __builtin_amdgcn_s_barrier();
        __builtin_amdgcn_sched_barrier(0);

        const _Float16* L = lds + cur * 8192;
        halfv8 aa[4], bb[4];
#pragma unroll
        for (int i = 0; i < 4; i++) {
            aa[i] = *(const halfv8*)(L +        aoff[i]);
            bb[i] = *(const halfv8*)(L + 4096 + boff[i]);
        }
#pragma unroll
        for (int mi = 0; mi < 4; mi++)
#pragma unroll
            for (int nj = 0; nj < 4; nj++)
                acc[mi][nj] = __builtin_amdgcn_mfma_f32_16x16x32_f16(aa[mi], bb[nj], acc[mi][nj], 0, 0, 0);

        asm volatile("s_waitcnt lgkmcnt(0)" ::: "memory");
        __builtin_amdgcn_sched_barrier(0);
        __builtin_amdgcn_s_barrier();
    }
#undef STAGEH_
}

#define ACC_INIT(acc) \
    _Pragma("unroll") for (int i = 0; i < 4; i++) \
    _Pragma("unroll") for (int j = 0; j < 4; j++) \
    _Pragma("unroll") for (int q = 0; q < 4; q++) acc[i][j][q] = 0.f;

#define EPI_VARS \
    const int lane = threadIdx.x & 63, wave = threadIdx.x >> 6; \
    const int wm = wave >> 1, wn = wave & 1, lr = lane & 15, lc = lane >> 4;

// ---- Router hidden GEMM, split-K x4 (frozen numerics), occ 4 blocks/CU ----
__global__ __launch_bounds__(256, 4) void gemm_router(
    const ushort* __restrict__ xh, const ushort* __restrict__ xl,
    const ushort* __restrict__ wr1h, const ushort* __restrict__ wr1l,
    float* __restrict__ hpart)
{
    __shared__ ushort lds[32768];
    floatv4 acc[4][4];
    ACC_INIT(acc)

    const int lid = blockIdx.x + 4 * (blockIdx.y + 16 * blockIdx.z);
    const int nid = (lid & 7) * 32 + (lid >> 3);
    const int kz = nid >> 6;
    const int rem = nid & 63;
    const int brow = (rem >> 2) * 128, bcol = (rem & 3) * 128;

    const int koff = kz * 256;
    gemm_core_bf(xh + koff, xl + koff, wr1h + koff, wr1l + koff,
                 D_, 256, brow, bcol, lds, acc);

    float* C = hpart + (size_t)kz * ND2;
    EPI_VARS
#pragma unroll
    for (int mi = 0; mi < 4; mi++)
#pragma unroll
        for (int nj = 0; nj < 4; nj++)
#pragma unroll
            for (int i = 0; i < 4; i++) {
                int row = brow + wm * 64 + mi * 16 + lc * 4 + i;
                int col = bcol + wn * 64 + nj * 16 + lr;
                C[(size_t)row * D2_ + col] = acc[mi][nj][i];
            }
}

// ---- Fused projections (fp16): z 0..7 dense K/V, z 8..11 gathered Q ----
// grid (8,16,12)=1536 blocks, XCD swizzle cpx=192, occ 4 blocks/CU
__global__ __launch_bounds__(256, 4) void gemm_proj(
    const _Float16* __restrict__ xf,
    const _Float16* __restrict__ wth,
    const float* __restrict__ bq, const float* __restrict__ bk, const float* __restrict__ bv,
    const int* __restrict__ idx, const int* __restrict__ meta,
    _Float16* __restrict__ qf, _Float16* __restrict__ kf, _Float16* __restrict__ vf)
{
    __shared__ _Float16 lds[16384];
    const int lid = blockIdx.x + 8 * (blockIdx.y + 16 * blockIdx.z);
    const int nid = (lid & 7) * 192 + (lid >> 3);
    const int z = nid >> 7;
    const int rem = nid & 127;
    const int brow = (rem >> 3) * 128, bcol = (rem & 7) * 128;

    if (z < 8) {
        const int slot = z >> 1, m = z & 1;
        const size_t so = (size_t)slot * TDE;
        const _Float16* Bm = wth + (size_t)(slot * 4 + 1 + m) * WWE;   // 1=K, 2=V
        const float* bias = ((m == 0) ? bk : bv) + (size_t)slot * D_;
        _Float16* Oo = ((m == 0) ? kf : vf) + so;

        floatv4 acc[4][4];
        ACC_INIT(acc)
        gemm_core_h1<false>(xf, Bm, nullptr, D_, D_, brow, bcol, lds, acc);

        EPI_VARS
#pragma unroll
        for (int mi = 0; mi < 4; mi++)
#pragma unroll
            for (int nj = 0; nj < 4; nj++)
#pragma unroll
                for (int i = 0; i < 4; i++) {
                    int row = brow + wm * 64 + mi * 16 + lc * 4 + i;
                    int col = bcol + wn * 64 + nj * 16 + lr;
                    Oo[(size_t)row * D_ + col] = (_Float16)(acc[mi][nj][i] + bias[col]);
                }
    } else {
        const int e = z - 8;
        const int pcnt = meta[32 + e];
        if (brow >= pcnt) return;
        const int* arow = idx + e * 2048 + brow;
        const _Float16* Bm = wth + (size_t)(e * 4 + 0) * WWE;
        const float* bias = bq + (size_t)e * D_;
        const size_t so = (size_t)e * TDE;

        floatv4 acc[4][4];
        ACC_INIT(acc)
        gemm_core_h1<true>(xf, Bm, arow, D_, D_, brow, bcol, lds, acc);

        EPI_VARS
#pragma unroll
        for (int mi = 0; mi < 4; mi++)
#pragma unroll
            for (int nj = 0; nj < 4; nj++)
#pragma unroll
                for (int i = 0; i < 4; i++) {
                    int row = brow + wm * 64 + mi * 16 + lc * 4 + i;   // slot
                    int col = bcol + wn * 64 + nj * 16 + lr;
                    qf[so + (size_t)row * D_ + col] =
                        (_Float16)((acc[mi][nj][i] + bias[col]) * 0.125f);
                }
    }
}

// ---- Output projection on compacted rows, scatter into out2[rank] slice ----
// grid (8,16,4)=512 blocks, XCD swizzle cpx=64, occ 4 blocks/CU.
// Every token has exactly 2 experts -> out2 fully covered, no memset needed.
__global__ __launch_bounds__(256, 4) void gemm_combine4(
    const _Float16* __restrict__ oh,
    const _Float16* __restrict__ wth,
    const float* __restrict__ bo, const float* __restrict__ emask,
    const int* __restrict__ idx, const int* __restrict__ meta,
    float* __restrict__ out2)
{
    __shared__ _Float16 lds[16384];
    const int lid = blockIdx.x + 8 * (blockIdx.y + 16 * blockIdx.z);
    const int nid = (lid & 7) * 64 + (lid >> 3);
    const int e = nid >> 7;
    const int rem = nid & 127;
    const int brow = (rem >> 3) * 128, bcol = (rem & 7) * 128;

    const int pcnt = meta[32 + e];
    if (brow >= pcnt) return;
    const size_t so = (size_t)e * TDE;
    const _Float16* Bm = wth + (size_t)(e * 4 + 3) * WWE;
    const float* bias = bo + (size_t)e * D_;
    const int* idxe = idx + e * 2048;

    floatv4 acc[4][4];
    ACC_INIT(acc)
    gemm_core_h1<false>(oh + so, Bm, nullptr, D_, D_, brow, bcol, lds, acc);

    EPI_VARS
#pragma unroll
    for (int mi = 0; mi < 4; mi++)
#pragma unroll
        for (int nj = 0; nj < 4; nj++)
#pragma unroll
            for (int i = 0; i < 4; i++) {
                int srow = brow + wm * 64 + mi * 16 + lc * 4 + i;
                int raw = idxe[srow];
                if (raw >= 0) {   // bit31 = pad flag
                    int row = raw & 0xFFFF;
                    int rank = (raw >> 30) & 1;
                    float s = emask[(size_t)row * E_ + e];
                    int col = bcol + wn * 64 + nj * 16 + lr;
                    out2[(size_t)rank * TDE + (size_t)row * D_ + col] =
                        s * (acc[mi][nj][i] + bias[col]);
                }
            }
}

// ---- reduce out2 slices -> out ----
__global__ __launch_bounds__(256) void reduce_out(
    const float* __restrict__ out2, float* __restrict__ out)
{
    size_t i = (size_t)blockIdx.x * 256 + threadIdx.x;
    const float4* p = (const float4*)out2;
    float4 a = p[i], b = p[i + TDE / 4];
    float4 r;
    r.x = a.x + b.x;
    r.y = a.y + b.y;
    r.z = a.z + b.z;
    r.w = a.w + b.w;
    ((float4*)out)[i] = r;
}

// ---------------------------------------------------------------------------
// Per-(expert,batch) routed-token lists, 64-padded, deterministic order.
// Entry = token | rank<<30 | (bit31 if pad); rank = index of e among the
// token's nonzero experts (0 or 1, by ascending expert id).
// ---------------------------------------------------------------------------
__global__ __launch_bounds__(256) void build_lists(
    const float* __restrict__ emask, int* __restrict__ idx, int* __restrict__ meta)
{
    const int e = blockIdx.x;
    const int tid = threadIdx.x;
    __shared__ int scan[256];
    __shared__ int runsh;
    if (tid == 0) runsh = 0;
    int* idxe = idx + e * 2048;

    for (int b = 0; b < B_; b++) {
        __syncthreads();
        const int base = runsh;
        int t0 = b * 512 + tid * 2;
        int f0 = (emask[(size_t)t0 * E_ + e] != 0.f) ? 1 : 0;
        int f1 = (emask[(size_t)(t0 + 1) * E_ + e] != 0.f) ? 1 : 0;
        int my = f0 + f1;
        scan[tid] = my;
        __syncthreads();
        for (int off = 1; off < 256; off <<= 1) {
            int v = (tid >= off) ? scan[tid - off] : 0;
            __syncthreads();
            scan[tid] += v;
            __syncthreads();
        }
        int excl = scan[tid] - my;
        int cnt = scan[255];
        if (f0) {
            int rank = 0;
            for (int ep = 0; ep < e; ep++)
                if (emask[(size_t)t0 * E_ + ep] != 0.f) rank = 1;
            idxe[base + excl] = t0 | (rank << 30);
        }
        if (f1) {
            int rank = 0;
            for (int ep = 0; ep < e; ep++)
                if (emask[(size_t)(t0 + 1) * E_ + ep] != 0.f) rank = 1;
            idxe[base + excl + f0] = (t0 + 1) | (rank << 30);
        }
        int plen = (cnt + 63) & ~63;
        for (int i = cnt + tid; i < plen; i += 256)
            idxe[base + i] = (b * 512) | (int)0x80000000;
        if (tid == 0) {
            meta[e * 4 + b] = base;
            meta[16 + e * 4 + b] = plen >> 6;
            runsh = base + plen;
        }
    }
    __syncthreads();
    int total = runsh;
    if (tid == 0) meta[32 + e] = total;
    for (int i = total + tid; i < 2048; i += 256)
        idxe[i] = (int)0x80000000;
}

// ---------------------------------------------------------------------------
// MFMA flash attention, single-fp16. grid (8,64,4), XCD swizzle cpx=256,
// occ 3 blocks/CU (26KB LDS). Per-(e,b) Q-tile count from meta; K/V dense.
// ---------------------------------------------------------------------------
__global__ __launch_bounds__(256, 3) void attn_all(
    const _Float16* __restrict__ qf_, const _Float16* __restrict__ kf_,
    const _Float16* __restrict__ vf_,
    _Float16* __restrict__ oh_,
    const int* __restrict__ meta)
{
    const int lid = blockIdx.x + 8 * (blockIdx.y + 64 * blockIdx.z);
    const int nid = (lid & 7) * 256 + (lid >> 3);
    const int e = nid >> 9;
    const int rem = nid & 511;
    const int bhid = rem >> 3, qtile = rem & 7;
    const int bb = bhid >> 4, hh = bhid & 15;

    const int ptiles = meta[16 + e * 4 + bb];
    if (qtile >= ptiles) return;
    const int pstart = meta[e * 4 + bb];

    __shared__ _Float16 Kf[4096];       // [64][64] f16, chunk-swizzled
    __shared__ _Float16 Vt[64 * 72];    // [d][k+pad]
    __shared__ _Float16 Pw[4][16 * 72]; // per-wave P

    const size_t zo = (size_t)e * TDE;
    const int tid = threadIdx.x;
    const int wave = tid >> 6, lane = tid & 63;
    const int lr = lane & 15, lc = lane >> 4;
    const int q0 = pstart + qtile * 64;
    const size_t kvbase = zo + (size_t)bb * S_ * D_ + hh * 64;
    const size_t qobase = zo + hh * 64;

    halfv8 qq[2];
    {
        size_t qoff = qobase + (size_t)(q0 + wave * 16 + lr) * D_ + lc * 8;
        qq[0] = *(const halfv8*)(qf_ + qoff);
        qq[1] = *(const halfv8*)(qf_ + qoff + 32);
    }

    floatv4 ov[4];
    float m4[4], l4[4];
#pragma unroll
    for (int df = 0; df < 4; df++)
#pragma unroll
        for (int i = 0; i < 4; i++) ov[df][i] = 0.f;
#pragma unroll
    for (int i = 0; i < 4; i++) { m4[i] = -3.0e38f; l4[i] = 0.f; }

    for (int kt = 0; kt < S_ / 64; kt++) {
        const int kk0 = kt * 64;
        __syncthreads();

#pragma unroll
        for (int s = 0; s < 2; s++) {
            int p = s * 256 + tid;
            int r = p >> 3;
            int c = (p & 7) ^ (r & 7);
            gload16(kf_ + kvbase + (size_t)(kk0 + r) * D_ + c * 8, Kf + p * 8);
        }
        {
            const _Float16* vsrc = vf_ + kvbase + (size_t)(kk0 + lane) * D_ + wave * 16;
            halfv8 v0 = *(const halfv8*)vsrc;
            halfv8 v1 = *(const halfv8*)(vsrc + 8);
#pragma unroll
            for (int j = 0; j < 8; j++) Vt[(wave * 16 + j) * 72 + lane] = v0[j];
#pragma unroll
            for (int j = 0; j < 8; j++) Vt[(wave * 16 + 8 + j) * 72 + lane] = v1[j];
        }
        __syncthreads();

        floatv4 sc[4];
#pragma unroll
        for (int n = 0; n < 4; n++)
#pragma unroll
            for (int i = 0; i < 4; i++) sc[n][i] = 0.f;
#pragma unroll
        for (int n = 0; n < 4; n++)
#pragma unroll
            for (int ds = 0; ds < 2; ds++) {
                int off = (16 * n + lr) * 64 + (((ds * 4 + lc) ^ (lr & 7)) * 8);
                halfv8 kr = *(const halfv8*)(Kf + off);
                sc[n] = __builtin_amdgcn_mfma_f32_16x16x32_f16(qq[ds], kr, sc[n], 0, 0, 0);
            }

        float tm[4];
#pragma unroll
        for (int i = 0; i < 4; i++)
            tm[i] = fmaxf(fmaxf(sc[0][i], sc[1][i]), fmaxf(sc[2][i], sc[3][i]));
#pragma unroll
        for (int off = 1; off <= 8; off <<= 1)
#pragma unroll
            for (int i = 0; i < 4; i++)
                tm[i] = fmaxf(tm[i], __shfl_xor(tm[i], off));

        float nm[4], sca[4], ps[4];
#pragma unroll
        for (int i = 0; i < 4; i++) {
            nm[i] = fmaxf(m4[i], tm[i]);
            sca[i] = __expf(m4[i] - nm[i]);
            ps[i] = 0.f;
        }
        float pval[4][4];
#pragma unroll
        for (int n = 0; n < 4; n++)
#pragma unroll
            for (int i = 0; i < 4; i++) {
                float p = __expf(sc[n][i] - nm[i]);
                pval[n][i] = p;
                ps[i] += p;
            }
#pragma unroll
        for (int off = 1; off <= 8; off <<= 1)
#pragma unroll
            for (int i = 0; i < 4; i++)
                ps[i] += __shfl_xor(ps[i], off);
#pragma unroll
        for (int i = 0; i < 4; i++) {
            l4[i] = l4[i] * sca[i] + ps[i];
            m4[i] = nm[i];
        }
#pragma unroll
        for (int df = 0; df < 4; df++)
#pragma unroll
            for (int i = 0; i < 4; i++) ov[df][i] *= sca[i];

#pragma unroll
        for (int n = 0; n < 4; n++)
#pragma unroll
            for (int i = 0; i < 4; i++)
                Pw[wave][(lc * 4 + i) * 72 + 16 * n + lr] = (_Float16)pval[n][i];
        __syncthreads();

#pragma unroll
        for (int ks = 0; ks < 2; ks++) {
            halfv8 pa = *(const halfv8*)(&Pw[wave][lr * 72 + ks * 32 + lc * 8]);
#pragma unroll
            for (int df = 0; df < 4; df++) {
                halfv8 vr = *(const halfv8*)(Vt + (df * 16 + lr) * 72 + ks * 32 + lc * 8);
                ov[df] = __builtin_amdgcn_mfma_f32_16x16x32_f16(pa, vr, ov[df], 0, 0, 0);
            }
        }
    }

#pragma unroll
    for (int df = 0; df < 4; df++)
#pragma unroll
        for (int i = 0; i < 4; i++) {
            float val = ov[df][i] / l4[i];
            size_t off = qobase + (size_t)(q0 + wave * 16 + lc * 4 + i) * D_ + df * 16 + lr;
            oh_[off] = (_Float16)val;
        }
}

// ---------------------------------------------------------------------------
// Split x: bf16 hi/lo (router path) + single fp16 (main path)
// ---------------------------------------------------------------------------
__global__ __launch_bounds__(256) void split_f32(
    const float* __restrict__ in, ushort* __restrict__ hb, ushort* __restrict__ lb,
    _Float16* __restrict__ hf)
{
    int i = blockIdx.x * 256 + threadIdx.x;
    float4 v = ((const float4*)in)[i];
    float vv[4] = {v.x, v.y, v.z, v.w};
    ushortv4 hv, lv;
    halfv4 hhv;
#pragma unroll
    for (int j = 0; j < 4; j++) {
        ushort h = f2bf(vv[j]);
        hv[j] = h;
        lv[j] = f2bf(vv[j] - bf2f(h));
        hhv[j] = (_Float16)vv[j];
    }
    ((ushortv4*)hb)[i] = hv;
    ((ushortv4*)lb)[i] = lv;
    ((halfv4*)hf)[i] = hhv;
}

// ---------------------------------------------------------------------------
// Router weight transpose + bf16 split (frozen)
// ---------------------------------------------------------------------------
__global__ __launch_bounds__(256) void tsplit(
    const float* __restrict__ W, ushort* __restrict__ Th, ushort* __restrict__ Tl,
    int K, int N)
{
    __shared__ float tile[64][65];
    const int n0 = blockIdx.x * 64, k0 = blockIdx.y * 64;
    const int tid = threadIdx.x;
#pragma unroll
    for (int i = 0; i < 16; i++) {
        int idx = i * 256 + tid;
        int r = idx >> 6, c = idx & 63;
        tile[r][c] = W[(size_t)(k0 + r) * N + n0 + c];
    }
    __syncthreads();
#pragma unroll
    for (int i = 0; i < 16; i++) {
        int idx = i * 256 + tid;
        int rn = idx >> 6, ck = idx & 63;
        float v = tile[ck][rn];
        ushort h = f2bf(v);
        Th[(size_t)(n0 + rn) * K + k0 + ck] = h;
        Tl[(size_t)(n0 + rn) * K + k0 + ck] = f2bf(v - bf2f(h));
    }
}

// ---- attention weights: transpose + single-fp16 round ----
__global__ __launch_bounds__(256) void tsplit16h(
    const float* __restrict__ Wq, const float* __restrict__ Wk,
    const float* __restrict__ Wv, const float* __restrict__ Wo,
    _Float16* __restrict__ Th)
{
    __shared__ float tile[64][65];
    const int mg = blockIdx.z;
    const int e = mg >> 2, m = mg & 3;
    const float* W = ((m == 0) ? Wq : (m == 1) ? Wk : (m == 2) ? Wv : Wo) + (size_t)e * WWE;
    _Float16* T = Th + (size_t)mg * WWE;
    const int n0 = blockIdx.x * 64, k0 = blockIdx.y * 64;
    const int tid = threadIdx.x;
#pragma unroll
    for (int i = 0; i < 16; i++) {
        int idx = i * 256 + tid;
        int r = idx >> 6, c = idx & 63;
        tile[r][c] = W[(size_t)(k0 + r) * D_ + n0 + c];
    }
    __syncthreads();
#pragma unroll
    for (int i = 0; i < 16; i++) {
        int idx = i * 256 + tid;
        int rn = idx >> 6, ck = idx & 63;
        T[(size_t)(n0 + rn) * D_ + k0 + ck] = (_Float16)tile[ck][rn];
    }
}

// ---------------------------------------------------------------------------
// Router post (frozen)
// ---------------------------------------------------------------------------
__global__ __launch_bounds__(256) void router_post(
    const float* __restrict__ hpart, const float* __restrict__ br1,
    const float* __restrict__ ln_g, const float* __restrict__ ln_b,
    const float* __restrict__ Wr2, const float* __restrict__ br2,
    float* __restrict__ emask)
{
    const int t = blockIdx.x;
    const int tid = threadIdx.x;
    __shared__ float red[256];
    __shared__ float logits[E_];

    const float* hp = hpart + (size_t)t * D2_;
    float x0 = hp[tid] + hp[ND2 + tid] + hp[2 * ND2 + tid] + hp[3 * ND2 + tid] + br1[tid];
    float x1 = hp[tid + 256] + hp[ND2 + tid + 256] + hp[2 * ND2 + tid + 256]
             + hp[3 * ND2 + tid + 256] + br1[tid + 256];

    red[tid] = x0 + x1; __syncthreads();
    for (int off = 128; off; off >>= 1) { if (tid < off) red[tid] += red[tid + off]; __syncthreads(); }
    float mu = red[0] * (1.f / 512.f);
    __syncthreads();

    float d0 = x0 - mu, d1 = x1 - mu;
    red[tid] = d0 * d0 + d1 * d1; __syncthreads();
    for (int off = 128; off; off >>= 1) { if (tid < off) red[tid] += red[tid + off]; __syncthreads(); }
    float rs = rsqrtf(red[0] * (1.f / 512.f) + 1e-5f);
    __syncthreads();

    float n0 = fmaxf(fmaf(d0 * rs, ln_g[tid],       ln_b[tid]),       0.f);
    float n1 = fmaxf(fmaf(d1 * rs, ln_g[tid + 256], ln_b[tid + 256]), 0.f);

    for (int e = 0; e < E_; e++) {
        red[tid] = n0 * Wr2[(size_t)tid * E_ + e] + n1 * Wr2[(size_t)(tid + 256) * E_ + e];
        __syncthreads();
        for (int off = 128; off; off >>= 1) { if (tid < off) red[tid] += red[tid + off]; __syncthreads(); }
        if (tid == 0) logits[e] = red[0] + br2[e];
        __syncthreads();
    }

    if (tid == 0) {
        float mx = fmaxf(fmaxf(logits[0], logits[1]), fmaxf(logits[2], logits[3]));
        float p[E_], sum = 0.f;
        for (int e = 0; e < E_; e++) { p[e] = expf(logits[e] - mx); sum += p[e]; }
        float inv = 1.f / sum;
        for (int e = 0; e < E_; e++) p[e] *= inv;
        int i1 = 0;
        for (int e = 1; e < E_; e++) if (p[e] > p[i1]) i1 = e;
        int i2 = -1;
        for (int e = 0; e < E_; e++) { if (e == i1) continue; if (i2 < 0 || p[e] > p[i2]) i2 = e; }
        float o[E_] = {0.f, 0.f, 0.f, 0.f};
        o[i1] = p[i1]; o[i2] = p[i2];
        for (int e = 0; e < E_; e++) emask[(size_t)t * E_ + e] = o[e];
    }
}

// ---------------------------------------------------------------------------
extern "C" void kernel_launch(void* const* d_in, const int* in_sizes, int n_in,
                              void* d_out, int out_size, void* d_ws, size_t ws_size,
                              hipStream_t stream) {
    const float* x   = (const float*)d_in[0];
    const float* Wq  = (const float*)d_in[1];
    const float* bq  = (const float*)d_in[2];
    const float* Wk  = (const float*)d_in[3];
    const float* bk  = (const float*)d_in[4];
    const float* Wv  = (const float*)d_in[5];
    const float* bv  = (const float*)d_in[6];
    const float* Wo  = (const float*)d_in[7];
    const float* bo  = (const float*)d_in[8];
    const float* Wr1 = (const float*)d_in[9];
    const float* br1 = (const float*)d_in[10];
    const float* lng = (const float*)d_in[11];
    const float* lnb = (const float*)d_in[12];
    const float* Wr2 = (const float*)d_in[13];
    const float* br2 = (const float*)d_in[14];

    float* out = (float*)d_out;
    char* w = (char*)d_ws;
    dim3 blk(256);
    const size_t MB = 1024ull * 1024ull;

    // flat layout, ~143 MB
    float*    emask = (float*)w;                         // 32 KB
    int*      idx   = (int*)(w + 64 * 1024);             // 32 KB
    int*      meta  = (int*)(w + 96 * 1024);             // 144 B
    _Float16* wth   = (_Float16*)(w + 1 * MB);           // 32 MB (16 mats f16)
    ushort*   wr1h  = (ushort*)(w + 33 * MB);            // 1 MB (router bf16)
    ushort*   wr1l  = (ushort*)(w + 34 * MB);
    ushort*   xh    = (ushort*)(w + 35 * MB);            // 4 MB (router bf16)
    ushort*   xl    = (ushort*)(w + 39 * MB);
    _Float16* xfh   = (_Float16*)(w + 43 * MB);          // 4 MB (main fp16)
    float*    hpart = (float*)(w + 47 * MB);             // 16 MB
    _Float16* qfb   = (_Float16*)(w + 63 * MB);          // 16 MB (4 experts)
    _Float16* kfb   = (_Float16*)(w + 79 * MB);
    _Float16* vfb   = (_Float16*)(w + 95 * MB);
    _Float16* ohb   = (_Float16*)(w + 111 * MB);
    float*    out2  = (float*)(w + 127 * MB);            // 16 MB -> ends 143 MB

    split_f32<<<dim3(NTOK * D_ / 1024), blk, 0, stream>>>(x, xh, xl, xfh);
    tsplit<<<dim3(D2_ / 64, D_ / 64), blk, 0, stream>>>(Wr1, wr1h, wr1l, D_, D2_);
    tsplit16h<<<dim3(16, 16, 16), blk, 0, stream>>>(Wq, Wk, Wv, Wo, wth);

    gemm_router<<<dim3(D2_ / 128, NTOK / 128, 4), blk, 0, stream>>>(
        xh, xl, wr1h, wr1l, hpart);
    router_post<<<dim3(NTOK), blk, 0, stream>>>(hpart, br1, lng, lnb, Wr2, br2, emask);
    build_lists<<<dim3(E_), blk, 0, stream>>>(emask, idx, meta);

    gemm_proj<<<dim3(D_ / 128, NTOK / 128, 12), blk, 0, stream>>>(
        xfh, wth, bq, bk, bv, idx, meta, qfb, kfb, vfb);

    attn_all<<<dim3(S_ / 64, B_ * H_, E_), blk, 0, stream>>>(
        qfb, kfb, vfb, ohb, meta);

    gemm_combine4<<<dim3(D_ / 128, NTOK / 128, 4), blk, 0, stream>>>(
        ohb, wth, bo, emask, idx, meta, out2);
    reduce_out<<<dim3(TDE / 1024), blk, 0, stream>>>(out2, out);
}